// Round 9
// baseline (579.380 us; speedup 1.0000x reference)
//
#include <hip/hip_runtime.h>
#include <hip/hip_bf16.h>

#define B_   8
#define KS_  64
#define L_   4096
#define D_   1024
#define H_   16
#define HD_  64
#define SCALE_ 0.125f

typedef __attribute__((ext_vector_type(8))) short short8;
typedef __attribute__((ext_vector_type(8))) unsigned short ushort8;
typedef __attribute__((ext_vector_type(4))) unsigned short ushort4v;
typedef __attribute__((ext_vector_type(4))) float f32x4;

__device__ __forceinline__ unsigned short f2b(float f) {
  union { float f; unsigned u; } v; v.f = f;
  unsigned r = v.u + 0x7fffu + ((v.u >> 16) & 1u);
  return (unsigned short)(r >> 16);
}

// HW packed fp32->bf16 RTNE (no builtin on gfx950; same rounding as f2b)
__device__ __forceinline__ unsigned cvtpk(float a, float b) {
  unsigned r;
  asm("v_cvt_pk_bf16_f32 %0, %1, %2" : "=v"(r) : "v"(a), "v"(b));
  return r;
}

typedef const __attribute__((address_space(1))) void gas_void;
typedef __attribute__((address_space(3))) void las_void;
__device__ __forceinline__ void gl2lds16(const void* g, void* l) {
  __builtin_amdgcn_global_load_lds((gas_void*)g, (las_void*)l, 16, 0, 0);
}

__device__ __forceinline__ void bar() {            // raw barrier: no vmcnt drain
  asm volatile("" ::: "memory");
  __builtin_amdgcn_s_barrier();
  asm volatile("" ::: "memory");
}
__device__ __forceinline__ void vm0()  { asm volatile("s_waitcnt vmcnt(0)"  ::: "memory"); }
__device__ __forceinline__ void vm2()  { asm volatile("s_waitcnt vmcnt(2)"  ::: "memory"); }
__device__ __forceinline__ void vm10() { asm volatile("s_waitcnt vmcnt(10)" ::: "memory"); }
__device__ __forceinline__ void lgkm0(){ asm volatile("s_waitcnt lgkmcnt(0)" ::: "memory"); }

// ---------------------------------------------------------------------------
// Convert: 4 x [1024x1024] weights + query [512x1024] fp32 -> bf16 in ws
// ---------------------------------------------------------------------------
__global__ __launch_bounds__(256) void wcvt(const float* __restrict__ wq,
                                            const float* __restrict__ wk,
                                            const float* __restrict__ wv,
                                            const float* __restrict__ wo,
                                            const float* __restrict__ query,
                                            unsigned short* __restrict__ wout,
                                            unsigned short* __restrict__ qout) {
  int i = blockIdx.x * 256 + threadIdx.x;        // 1,179,648 float4 units
  const float* src;
  unsigned short* dst;
  int off;
  if (i < (4 << 18)) {
    int seg = i >> 18;
    off = (i & 0x3ffff) << 2;
    src = (seg == 0) ? wq : (seg == 1) ? wk : (seg == 2) ? wv : wo;
    dst = wout + ((size_t)seg << 20);
  } else {
    off = (i - (4 << 18)) << 2;                  // 0 .. 524287
    src = query;
    dst = qout;
  }
  f32x4 v = *(const f32x4*)(src + off);
  ushort4v o;
#pragma unroll
  for (int j = 0; j < 4; ++j) o[j] = f2b(v[j]);
  *(ushort4v*)(dst + off) = o;
}

// ---------------------------------------------------------------------------
// 256x256 8-phase GEMM, fp32 A fused convert (T2+T3+T4+T5+T14):
//   C[M][1024](bf16) = A[M][1024](fp32) @ W[1024][1024]^T(bf16)
//  Identical to round 8 EXCEPT __launch_bounds__(512, 1):
//  the (512,2) bound capped VGPRs at 128 and spilled av[8] to scratch
//  (343 MB WRITE_SIZE, 2.2x slowdown). LDS (128 KB) limits occupancy to
//  1 block/CU regardless, so the cap bought nothing. With (512,1) the
//  allocator can hold av/af/bf/acc (~200 VGPR) without spill.
//  vmcnt ledger (A-loads + B-gl2lds share the queue; asm "memory" fences
//  pin program order). Steady state, GROUP(t) entry = [B2kh1(t), A8(t+1)]:
//   ph1: LDA,LDB(kh0)                                  bar MM0 bar
//   ph2: LDB; stage B-kh0(t+1); vmcnt(10)  <- B2kh1(t) landed (used ph3)
//   ph3: LDA,LDB(kh1)                                  bar MM0 bar
//   ph4: LDB; stage B-kh1(t+1); vmcnt(2)   <- A8(t+1)+B2kh0(t+1) landed
//        cvt+ds_write A(t+1); issue A8(t+2); lgkmcnt(0); bar MM1 bar
//  Never drains vmcnt to 0 in the main loop (T4). Last group: vm0/none.
// ---------------------------------------------------------------------------
__global__ __launch_bounds__(512, 1) void gemm256f(const float* __restrict__ A,
                                                   const unsigned short* __restrict__ W,
                                                   unsigned short* __restrict__ C) {
  __shared__ __align__(16) char smem[131072];
  const int tid = threadIdx.x, lane = tid & 63, w = tid >> 6;
  const int g = lane >> 4, c15 = lane & 15;
  const int wm = w >> 2, wn = w & 3;

  const int swz = (blockIdx.x & 7) * 64 + (blockIdx.x >> 3);
  const long m0 = (long)(swz >> 2) * 256;
  const int  n0 = (swz & 3) * 256;

  // staging rows: each thread owns rows srow and srow+128
  const int srow = w * 16 + (lane >> 2);
  // B source pre-swizzled (dest linear lane*16)
  const int cswz = (lane & 3) ^ ((lane >> 2) & 3);
  const unsigned short* b_sr = W + (long)(n0 + srow) * 1024 + cswz * 8;
  // A fp32 source: linear chunk lane&3; swizzle applied on ds_write side
  const float* a32 = A + (m0 + srow) * 1024 + (lane & 3) * 8;
  const int    c0  = ((lane & 3) ^ ((lane >> 2) & 3)) << 4;  // phys byte chunk

  // read addressing (swizzled), same as round-6
  const int rswz = (g ^ (c15 & 3)) << 4;
  const int aoff = (wm * 128 + c15) * 64 + rswz;
  const int boff = 65536 + (wn * 64 + c15) * 64 + rswz;

  f32x4 acc[8][4] = {};
  short8 af[8], bf[2];
  f32x4 av[8];

  auto STAGE_B = [&](int d, int kh, int tk) {
    char* dst = smem + 65536 + d * 32768 + kh * 16384 + w * 1024;
    const unsigned short* src = b_sr + tk * 64 + kh * 32;
    gl2lds16(src,          dst);
    gl2lds16(src + 131072, dst + 8192);
  };
  auto ISSUE_A = [&](int tk) {
    const float* p = a32 + tk * 64;
    av[0] = *(const f32x4*)(p);
    av[1] = *(const f32x4*)(p + 4);
    av[2] = *(const f32x4*)(p + 131072);
    av[3] = *(const f32x4*)(p + 131072 + 4);
    av[4] = *(const f32x4*)(p + 32);
    av[5] = *(const f32x4*)(p + 36);
    av[6] = *(const f32x4*)(p + 131072 + 32);
    av[7] = *(const f32x4*)(p + 131072 + 36);
  };
  auto CVTWRITE_A = [&](int d) {
    char* b0 = smem + d * 32768;                 // kh0
    char* b1 = b0 + 16384;                       // kh1
    union { unsigned u[4]; ushort8 s; } t0, t1, t2, t3;
    t0.u[0] = cvtpk(av[0][0], av[0][1]); t0.u[1] = cvtpk(av[0][2], av[0][3]);
    t0.u[2] = cvtpk(av[1][0], av[1][1]); t0.u[3] = cvtpk(av[1][2], av[1][3]);
    t1.u[0] = cvtpk(av[2][0], av[2][1]); t1.u[1] = cvtpk(av[2][2], av[2][3]);
    t1.u[2] = cvtpk(av[3][0], av[3][1]); t1.u[3] = cvtpk(av[3][2], av[3][3]);
    t2.u[0] = cvtpk(av[4][0], av[4][1]); t2.u[1] = cvtpk(av[4][2], av[4][3]);
    t2.u[2] = cvtpk(av[5][0], av[5][1]); t2.u[3] = cvtpk(av[5][2], av[5][3]);
    t3.u[0] = cvtpk(av[6][0], av[6][1]); t3.u[1] = cvtpk(av[6][2], av[6][3]);
    t3.u[2] = cvtpk(av[7][0], av[7][1]); t3.u[3] = cvtpk(av[7][2], av[7][3]);
    *(ushort8*)(b0 + srow * 64 + c0)        = t0.s;
    *(ushort8*)(b0 + srow * 64 + 8192 + c0) = t1.s;   // +128 rows
    *(ushort8*)(b1 + srow * 64 + c0)        = t2.s;
    *(ushort8*)(b1 + srow * 64 + 8192 + c0) = t3.s;
  };
  auto LDA = [&](int d, int ks) {
    const char* base = smem + d * 32768 + ks * 16384 + aoff;
#pragma unroll
    for (int m = 0; m < 8; ++m) af[m] = *(const short8*)(base + m * 1024);
  };
  auto LDB = [&](int d, int ks, int nh) {
    const char* base = smem + d * 32768 + ks * 16384 + boff + nh * 2048;
    bf[0] = *(const short8*)(base);
    bf[1] = *(const short8*)(base + 1024);
  };
  auto MM = [&](int nh) {
    __builtin_amdgcn_s_setprio(1);
#pragma unroll
    for (int n2 = 0; n2 < 2; ++n2)
#pragma unroll
      for (int m = 0; m < 8; ++m)
        acc[m][nh * 2 + n2] =
            __builtin_amdgcn_mfma_f32_16x16x32_bf16(af[m], bf[n2], acc[m][nh * 2 + n2], 0, 0, 0);
    __builtin_amdgcn_s_setprio(0);
  };

  auto GROUP = [&](int d, int tk, bool stage, bool issue2, bool last) {
    // ph1
    LDA(d, 0); LDB(d, 0, 0);
    bar(); MM(0); bar();
    // ph2
    LDB(d, 0, 1);
    if (stage) STAGE_B(d ^ 1, 0, tk + 1);
    if (last) vm0(); else vm10();
    bar(); MM(1); bar();
    // ph3
    LDA(d, 1); LDB(d, 1, 0);
    bar(); MM(0); bar();
    // ph4
    LDB(d, 1, 1);
    if (stage) {
      STAGE_B(d ^ 1, 1, tk + 1);
      vm2();                       // A8(t+1) + B-kh0(t+1) landed
      CVTWRITE_A(d ^ 1);
      if (issue2) ISSUE_A(tk + 2);
      lgkm0();                     // publish ds_writes before barrier
    }
    bar(); MM(1); bar();
  };

  // prologue: tile 0 -> buf0. queue ledger in comments.
  ISSUE_A(0);                      // [A8(0)] = 8
  STAGE_B(0, 0, 0);                // [A8(0), B2kh0(0)] = 10
  vm2();                           // A8(0) done, [B2kh0(0)]
  CVTWRITE_A(0);
  STAGE_B(0, 1, 0);                // [B2kh0(0), B2kh1(0)] = 4
  ISSUE_A(1);                      // [B2kh0(0), B2kh1(0), A8(1)] = 12
  vm10();                          // B2kh0(0) done
  lgkm0();
  bar();                           // entry invariant: [B2kh1(0), A8(1)] = 10

#pragma unroll 1
  for (int tk = 0; tk < 14; tk += 2) {   // tiles 0..13: full staging+issue
    GROUP(0, tk,     true, true,  false);
    GROUP(1, tk + 1, true, true,  false);
  }
  GROUP(0, 14, true,  false, false);     // stages 15, no A(16)
  GROUP(1, 15, false, false, true);      // drain

  // epilogue: acc -> c_lds [256][256] -> coalesced stores
  unsigned short* cl = (unsigned short*)smem;
#pragma unroll
  for (int m = 0; m < 8; ++m)
#pragma unroll
    for (int n = 0; n < 4; ++n)
#pragma unroll
      for (int r = 0; r < 4; ++r)
        cl[(wm * 128 + m * 16 + g * 4 + r) * 256 + wn * 64 + n * 16 + c15] =
            f2b(acc[m][n][r]);
  __syncthreads();
  const int row = tid >> 1, half = tid & 1;
  unsigned short*       dst = C + (m0 + row) * 1024 + n0 + half * 128;
  const unsigned short* sl  = cl + row * 256 + half * 128;
#pragma unroll
  for (int i = 0; i < 16; ++i)
    *(ushort8*)(dst + i * 8) = *(const ushort8*)(sl + i * 8);
}

// ---------------------------------------------------------------------------
// 128x128 2-phase GEMM (round-3 proven) for the small projections (M=512)
// ---------------------------------------------------------------------------
template <bool OUT_F32B>
__global__ __launch_bounds__(256) void gemm_bf16(const unsigned short* __restrict__ A,
                                                 const unsigned short* __restrict__ W,
                                                 void* __restrict__ Cp,
                                                 const float* __restrict__ bias) {
  __shared__ __align__(16) char smem[34816];
  const int tid = threadIdx.x, lane = tid & 63, wv = tid >> 6;
  const int g = lane >> 4, c15 = lane & 15;
  const int wm = wv >> 1, wn = wv & 1;

  const int nwg = gridDim.x;
  const int swz = (blockIdx.x & 7) * (nwg >> 3) + (blockIdx.x >> 3);
  const long m0 = (long)(swz >> 3) * 128;
  const int  n0 = (swz & 7) * 128;

  const int srow = lane >> 2, scol = (lane & 3) * 8;
  const unsigned short* a_src = A + (m0 + srow) * 1024 + scol;
  const unsigned short* b_src = W + (long)(n0 + srow) * 1024 + scol;

  f32x4 acc[4][4] = {};

  auto stage = [&](int buf, int kt) {
    unsigned short* al = (unsigned short*)(smem + buf * 8192);
    unsigned short* bl = (unsigned short*)(smem + 16384 + buf * 8192);
#pragma unroll
    for (int q = 0; q < 2; ++q) {
      const int rbase = q * 64 + wv * 16;
      gl2lds16(a_src + (long)rbase * 1024 + kt * 32, al + rbase * 32);
      gl2lds16(b_src + (long)rbase * 1024 + kt * 32, bl + rbase * 32);
    }
  };

  stage(0, 0);
  __syncthreads();

  int cur = 0;
  for (int kt = 0; kt < 32; ++kt) {
    if (kt + 1 < 32) stage(cur ^ 1, kt + 1);
    const unsigned short* al = (const unsigned short*)(smem + cur * 8192);
    const unsigned short* bl = (const unsigned short*)(smem + 16384 + cur * 8192);
    short8 af[4];
#pragma unroll
    for (int m = 0; m < 4; ++m)
      af[m] = *(const short8*)&al[(wm * 64 + m * 16 + c15) * 32 + g * 8];
#pragma unroll
    for (int n = 0; n < 4; ++n) {
      short8 b8 = *(const short8*)&bl[(wn * 64 + n * 16 + c15) * 32 + g * 8];
#pragma unroll
      for (int m = 0; m < 4; ++m)
        acc[m][n] = __builtin_amdgcn_mfma_f32_16x16x32_bf16(af[m], b8, acc[m][n], 0, 0, 0);
    }
    __syncthreads();
    cur ^= 1;
  }

  if constexpr (OUT_F32B) {
    float* Cf = (float*)Cp;
#pragma unroll
    for (int m = 0; m < 4; ++m)
#pragma unroll
      for (int n = 0; n < 4; ++n)
#pragma unroll
        for (int r = 0; r < 4; ++r) {
          long row = m0 + wm * 64 + m * 16 + g * 4 + r;
          int  col = n0 + wn * 64 + n * 16 + c15;
          Cf[row * 1024 + col] = acc[m][n][r] + bias[col];
        }
  } else {
    unsigned short* c_lds = (unsigned short*)smem;
#pragma unroll
    for (int m = 0; m < 4; ++m)
#pragma unroll
      for (int n = 0; n < 4; ++n)
#pragma unroll
        for (int r = 0; r < 4; ++r)
          c_lds[(wm * 64 + m * 16 + g * 4 + r) * 132 + wn * 64 + n * 16 + c15] =
              f2b(acc[m][n][r]);
    __syncthreads();
    unsigned short* Cb = (unsigned short*)Cp;
    const int row = tid >> 1, half = tid & 1;
    unsigned short*       dst = Cb + (m0 + row) * 1024 + n0 + half * 64;
    const unsigned short* sl  = &c_lds[row * 132 + half * 64];
#pragma unroll
    for (int i = 0; i < 8; ++i)
      *(ushort8*)(dst + i * 8) = *(const ushort8*)(sl + i * 8);
  }
}

// ---------------------------------------------------------------------------
// Attention pass 1 (L-split x4): partial rowsums over 1024 keys per block.
// ---------------------------------------------------------------------------
__global__ __launch_bounds__(512) void attn_pass1(const unsigned short* __restrict__ q_b,
                                                  const unsigned short* __restrict__ k_b,
                                                  float* __restrict__ rs_part) {
  __shared__ unsigned short q_lds[64][72];
  __shared__ unsigned short k_lds[128][72];
  __shared__ float rs_lds[8][64];
  const int bh = blockIdx.x >> 2, ch = blockIdx.x & 3;
  const int b = bh >> 4, h = bh & 15;
  const int tid = threadIdx.x;
  const int w = tid >> 6, lane = tid & 63;
  const int g = lane >> 4, c15 = lane & 15;

  {
    int slot = tid >> 3, cc = (tid & 7) * 8;
    *(ushort8*)&q_lds[slot][cc] =
        *(const ushort8*)(q_b + (long)(b * 64 + slot) * 1024 + h * 64 + cc);
  }

  float rs[4][4] = {};
  const long kbase = (long)b * L_ * D_ + h * 64;
  const int  sl = tid >> 2, sc = (tid & 3) * 16;

  for (int it = ch * 8; it < ch * 8 + 8; ++it) {
    const int l0 = it * 128;
    ushort8 k0 = *(const ushort8*)(k_b + kbase + (long)(l0 + sl) * 1024 + sc);
    ushort8 k1 = *(const ushort8*)(k_b + kbase + (long)(l0 + sl) * 1024 + sc + 8);
    __syncthreads();
    *(ushort8*)&k_lds[sl][sc]     = k0;
    *(ushort8*)&k_lds[sl][sc + 8] = k1;
    __syncthreads();

    f32x4 s[4] = {};
#pragma unroll
    for (int ks = 0; ks < 2; ++ks) {
      short8 bf = *(const short8*)&k_lds[w * 16 + c15][ks * 32 + g * 8];
#pragma unroll
      for (int m = 0; m < 4; ++m) {
        short8 af = *(const short8*)&q_lds[m * 16 + c15][ks * 32 + g * 8];
        s[m] = __builtin_amdgcn_mfma_f32_16x16x32_bf16(af, bf, s[m], 0, 0, 0);
      }
    }
    float mx = -1e30f;
#pragma unroll
    for (int m = 0; m < 4; ++m)
#pragma unroll
      for (int r = 0; r < 4; ++r) mx = fmaxf(mx, s[m][r]);
    mx = fmaxf(mx, __shfl_xor(mx, 16));
    mx = fmaxf(mx, __shfl_xor(mx, 32));
    float sum = 0.f, p[4][4];
#pragma unroll
    for (int m = 0; m < 4; ++m)
#pragma unroll
      for (int r = 0; r < 4; ++r) { p[m][r] = __expf((s[m][r] - mx) * SCALE_); sum += p[m][r]; }
    sum += __shfl_xor(sum, 16);
    sum += __shfl_xor(sum, 32);
    float rinv = 1.0f / sum;
#pragma unroll
    for (int m = 0; m < 4; ++m)
#pragma unroll
      for (int r = 0; r < 4; ++r) rs[m][r] += p[m][r] * rinv;
  }
#pragma unroll
  for (int m = 0; m < 4; ++m)
#pragma unroll
    for (int r = 0; r < 4; ++r) {
      float v = rs[m][r];
      v += __shfl_xor(v, 1); v += __shfl_xor(v, 2);
      v += __shfl_xor(v, 4); v += __shfl_xor(v, 8);
      if (c15 == 0) rs_lds[w][m * 16 + g * 4 + r] = v;
    }
  __syncthreads();
  if (tid < 64) {
    float t = 0.f;
#pragma unroll
    for (int w2 = 0; w2 < 8; ++w2) t += rs_lds[w2][tid];
    rs_part[(bh * 4 + ch) * 64 + tid] = t;
  }
}

// ---------------------------------------------------------------------------
// Attention pass 2 (L-split x4): recompute softmax, scale, write attn fp32,
// PV partial -> op_part fp32.
// ---------------------------------------------------------------------------
__global__ __launch_bounds__(512) void attn_pass2(const unsigned short* __restrict__ q_b,
                                                  const unsigned short* __restrict__ k_b,
                                                  const unsigned short* __restrict__ v_b,
                                                  const float* __restrict__ rs_part,
                                                  float* __restrict__ attn,
                                                  float* __restrict__ op_part) {
  __shared__ unsigned short q_lds[64][72];
  __shared__ unsigned short k_lds[128][72];
  __shared__ unsigned short vt_lds[64][136];
  __shared__ unsigned short pt_lds[64][136];
  const int bh = blockIdx.x >> 2, ch = blockIdx.x & 3;
  const int b = bh >> 4, h = bh & 15;
  const int tid = threadIdx.x;
  const int w = tid >> 6, lane = tid & 63;
  const int g = lane >> 4, c15 = lane & 15;

  {
    int slot = tid >> 3, cc = (tid & 7) * 8;
    *(ushort8*)&q_lds[slot][cc] =
        *(const ushort8*)(q_b + (long)(b * 64 + slot) * 1024 + h * 64 + cc);
  }

  float inv_r[4][4];
#pragma unroll
  for (int m = 0; m < 4; ++m)
#pragma unroll
    for (int r = 0; r < 4; ++r) {
      int slot = m * 16 + g * 4 + r;
      float s = 0.f;
#pragma unroll
      for (int c = 0; c < 4; ++c) s += rs_part[(bh * 4 + c) * 64 + slot];
      inv_r[m][r] = 1.0f / (s + 1e-8f);
    }

  f32x4 oacc[2] = {};
  const int m_pv = w >> 1, n_pv0 = (w & 1) * 2;
  float* attn_base = attn + (long)bh * KS_ * L_;
  const long base_bld = (long)b * L_ * D_ + h * 64;
  const int  sl = tid >> 2, sc = (tid & 3) * 16;

  for (int it = ch * 8; it < ch * 8 + 8; ++it) {
    const int l0 = it * 128;
    ushort8 k0 = *(const ushort8*)(k_b + base_bld + (long)(l0 + sl) * 1024 + sc);
    ushort8 k1 = *(const ushort8*)(k_b + base_bld + (long)(l0 + sl) * 1024 + sc + 8);
    ushort8 v0 = *(const ushort8*)(v_b + base_bld + (long)(l0 + sl) * 1024 + sc);
    ushort8 v1 = *(const ushort8*)(v_b + base_bld + (long)(l0 + sl) * 1024 + sc + 8);
    __syncthreads();
    *(ushort8*)&k_lds[sl][sc]     = k0;
    *(ushort8*)&k_lds[sl][sc + 8] = k1;
#pragma unroll
    for (int j = 0; j < 8; ++j) {
      vt_lds[sc + j][sl]     = v0[j];
      vt_lds[sc + 8 + j][sl] = v1[j];
    }
    __syncthreads();

    f32x4 s[4] = {};
#pragma unroll
    for (int ks = 0; ks < 2; ++ks) {
      short8 bf = *(const short8*)&k_lds[w * 16 + c15][ks * 32 + g * 8];
#pragma unroll
      for (int m = 0; m < 4; ++m) {
        short8 af = *(const short8*)&q_lds[m * 16 + c15][ks * 32 + g * 8];
        s[m] = __builtin_amdgcn_mfma_f32_16x16x32_bf16(af, bf, s[m], 0, 0, 0);
      }
    }
    float mx = -1e30f;
#pragma unroll
    for (int m = 0; m < 4; ++m)
#pragma unroll
      for (int r = 0; r < 4; ++r) mx = fmaxf(mx, s[m][r]);
    mx = fmaxf(mx, __shfl_xor(mx, 16));
    mx = fmaxf(mx, __shfl_xor(mx, 32));
    float sum = 0.f, p[4][4];
#pragma unroll
    for (int m = 0; m < 4; ++m)
#pragma unroll
      for (int r = 0; r < 4; ++r) { p[m][r] = __expf((s[m][r] - mx) * SCALE_); sum += p[m][r]; }
    sum += __shfl_xor(sum, 16);
    sum += __shfl_xor(sum, 32);
    float rinv = 1.0f / sum;

    const int lloc = w * 16 + c15;
#pragma unroll
    for (int m = 0; m < 4; ++m)
#pragma unroll
      for (int r = 0; r < 4; ++r) {
        float ps = p[m][r] * rinv * inv_r[m][r];
        attn_base[(long)(m * 16 + g * 4 + r) * L_ + l0 + lloc] = ps;
        pt_lds[m * 16 + g * 4 + r][lloc] = f2b(ps);
      }
    __syncthreads();

#pragma unroll
    for (int ks = 0; ks < 4; ++ks) {
      short8 pa = *(const short8*)&pt_lds[m_pv * 16 + c15][ks * 32 + g * 8];
#pragma unroll
      for (int n2 = 0; n2 < 2; ++n2) {
        short8 vb = *(const short8*)&vt_lds[(n_pv0 + n2) * 16 + c15][ks * 32 + g * 8];
        oacc[n2] = __builtin_amdgcn_mfma_f32_16x16x32_bf16(pa, vb, oacc[n2], 0, 0, 0);
      }
    }
  }

#pragma unroll
  for (int n2 = 0; n2 < 2; ++n2)
#pragma unroll
    for (int r = 0; r < 4; ++r) {
      int slot = m_pv * 16 + g * 4 + r;
      int c    = (n_pv0 + n2) * 16 + c15;
      op_part[((long)(bh * 4 + ch) * 64 + slot) * 64 + c] = oacc[n2][r];
    }
}

// ---------------------------------------------------------------------------
// Reduce PV chunk-partials -> oh bf16 [512][1024]
// ---------------------------------------------------------------------------
__global__ __launch_bounds__(256) void oh_red(const float* __restrict__ op_part,
                                              unsigned short* __restrict__ oh) {
  int i = blockIdx.x * 256 + threadIdx.x;
  int c = i & 63, slot = (i >> 6) & 63, bh = i >> 12;
  float s = 0.f;
#pragma unroll
  for (int ch = 0; ch < 4; ++ch)
    s += op_part[((long)(bh * 4 + ch) * 64 + slot) * 64 + c];
  int b = bh >> 4, h = bh & 15;
  oh[(long)(b * 64 + slot) * 1024 + h * 64 + c] = f2b(s);
}

// ---------------------------------------------------------------------------
extern "C" void kernel_launch(void* const* d_in, const int* in_sizes, int n_in,
                              void* d_out, int out_size, void* d_ws, size_t ws_size,
                              hipStream_t stream) {
  (void)in_sizes; (void)n_in; (void)out_size; (void)ws_size;
  const float* query = (const float*)d_in[0];
  const float* key   = (const float*)d_in[1];
  const float* value = (const float*)d_in[2];
  const float* Wq    = (const float*)d_in[3];
  const float* Wk    = (const float*)d_in[4];
  const float* Wv    = (const float*)d_in[5];
  const float* Wo    = (const float*)d_in[6];
  const float* bo    = (const float*)d_in[7];

  char* ws = (char*)d_ws;
  unsigned short* w_all   = (unsigned short*)ws;                        // 8 MB
  unsigned short* wq_b    = w_all;
  unsigned short* wk_b    = w_all + (1u << 20);
  unsigned short* wv_b    = w_all + (2u << 20);
  unsigned short* wo_b    = w_all + (3u << 20);
  unsigned short* qin_b   = (unsigned short*)(ws + ((size_t)8  << 20)); // 1 MB
  unsigned short* q_b     = (unsigned short*)(ws + ((size_t)9  << 20)); // 1 MB
  unsigned short* oh_b    = (unsigned short*)(ws + ((size_t)10 << 20)); // 1 MB
  float*          rs_part = (float*)         (ws + ((size_t)11 << 20)); // 128 KB
  float*          op_part = (float*)         (ws + ((size_t)12 << 20)); // 8 MB
  unsigned short* k_b     = (unsigned short*)(ws + ((size_t)20 << 20)); // 64 MB
  unsigned short* v_b     = (unsigned short*)(ws + ((size_t)84 << 20)); // 64 MB

  float* out  = (float*)d_out;
  float* attn = out + (size_t)B_ * KS_ * D_;

  wcvt<<<4608, 256, 0, stream>>>(Wq, Wk, Wv, Wo, query, w_all, qin_b);

  gemm_bf16<false><<<32, 256, 0, stream>>>(qin_b, wq_b, q_b, nullptr);
  gemm256f<<<512, 512, 0, stream>>>(key,   wk_b, k_b);
  gemm256f<<<512, 512, 0, stream>>>(value, wv_b, v_b);

  attn_pass1<<<512, 512, 0, stream>>>(q_b, k_b, rs_part);
  attn_pass2<<<512, 512, 0, stream>>>(q_b, k_b, v_b, rs_part, attn, op_part);
  oh_red<<<2048, 256, 0, stream>>>(op_part, oh_b);

  gemm_bf16<true><<<32, 256, 0, stream>>>(oh_b, wo_b, out, bo);
}

// Round 10
// 381.663 us; speedup vs baseline: 1.5180x; 1.5180x over previous
//
#include <hip/hip_runtime.h>
#include <hip/hip_bf16.h>

#define B_   8
#define KS_  64
#define L_   4096
#define D_   1024
#define H_   16
#define HD_  64
#define SCALE_ 0.125f

typedef __attribute__((ext_vector_type(8))) short short8;
typedef __attribute__((ext_vector_type(8))) unsigned short ushort8;
typedef __attribute__((ext_vector_type(4))) unsigned short ushort4v;
typedef __attribute__((ext_vector_type(4))) float f32x4;

__device__ __forceinline__ unsigned short f2b(float f) {
  union { float f; unsigned u; } v; v.f = f;
  unsigned r = v.u + 0x7fffu + ((v.u >> 16) & 1u);
  return (unsigned short)(r >> 16);
}

typedef const __attribute__((address_space(1))) void gas_void;
typedef __attribute__((address_space(3))) void las_void;
__device__ __forceinline__ void gl2lds16(const void* g, void* l) {
  __builtin_amdgcn_global_load_lds((gas_void*)g, (las_void*)l, 16, 0, 0);
}

__device__ __forceinline__ void bar() {           // raw barrier: no vmcnt drain
  asm volatile("" ::: "memory");
  __builtin_amdgcn_s_barrier();
  asm volatile("" ::: "memory");
}
__device__ __forceinline__ void vm4() {           // counted vmcnt (T4)
  asm volatile("s_waitcnt vmcnt(4)" ::: "memory");
}

// ---------------------------------------------------------------------------
// Convert: 4 x [1024x1024] weights + query [512x1024] fp32 -> bf16 in ws
// ---------------------------------------------------------------------------
__global__ __launch_bounds__(256) void wcvt(const float* __restrict__ wq,
                                            const float* __restrict__ wk,
                                            const float* __restrict__ wv,
                                            const float* __restrict__ wo,
                                            const float* __restrict__ query,
                                            unsigned short* __restrict__ wout,
                                            unsigned short* __restrict__ qout) {
  int i = blockIdx.x * 256 + threadIdx.x;        // 1,179,648 float4 units
  const float* src;
  unsigned short* dst;
  int off;
  if (i < (4 << 18)) {
    int seg = i >> 18;
    off = (i & 0x3ffff) << 2;
    src = (seg == 0) ? wq : (seg == 1) ? wk : (seg == 2) ? wv : wo;
    dst = wout + ((size_t)seg << 20);
  } else {
    off = (i - (4 << 18)) << 2;                  // 0 .. 524287
    src = query;
    dst = qout;
  }
  f32x4 v = *(const f32x4*)(src + off);
  ushort4v o;
#pragma unroll
  for (int j = 0; j < 4; ++j) o[j] = f2b(v[j]);
  *(ushort4v*)(dst + off) = o;
}

// ---------------------------------------------------------------------------
// Single-tensor streaming convert fp32 -> bf16: ONE read stream + ONE write
// stream per kernel (the 4-6 stream mixed version plateaued at 3.9 TB/s).
// unit = 8 f32 (2 x 16B nontemporal loads, 1 x 16B store). Grid-stride.
// ---------------------------------------------------------------------------
__global__ __launch_bounds__(256) void cvt1(const float* __restrict__ src,
                                            unsigned short* __restrict__ dst,
                                            int nunits) {
  const int stride = gridDim.x * 256;
  for (int i = blockIdx.x * 256 + threadIdx.x; i < nunits; i += stride) {
    const f32x4* p = (const f32x4*)(src + (size_t)i * 8);
    f32x4 a = __builtin_nontemporal_load(p);
    f32x4 b = __builtin_nontemporal_load(p + 1);
    ushort8 o;
#pragma unroll
    for (int j = 0; j < 4; ++j) { o[j] = f2b(a[j]); o[j + 4] = f2b(b[j]); }
    *(ushort8*)(dst + (size_t)i * 8) = o;
  }
}

// ---------------------------------------------------------------------------
// 256x256 8-phase GEMM (T2+T3+T4+T5): C[M][1024] = A(bf16) @ W(bf16)^T
//  Round-6 proven version (bf16 A via global_load_lds).
// ---------------------------------------------------------------------------
__global__ __launch_bounds__(512, 2) void gemm256(const unsigned short* __restrict__ A,
                                                  const unsigned short* __restrict__ W,
                                                  unsigned short* __restrict__ C) {
  __shared__ __align__(16) char smem[131072];
  const int tid = threadIdx.x, lane = tid & 63, w = tid >> 6;
  const int g = lane >> 4, c15 = lane & 15;
  const int wm = w >> 2, wn = w & 3;

  const int swz = (blockIdx.x & 7) * 64 + (blockIdx.x >> 3);
  const long m0 = (long)(swz >> 2) * 256;
  const int  n0 = (swz & 3) * 256;

  const int srow = w * 16 + (lane >> 2);
  const int cswz = (lane & 3) ^ ((lane >> 2) & 3);
  const unsigned short* a_sr = A + (m0 + srow) * 1024 + cswz * 8;
  const unsigned short* b_sr = W + (long)(n0 + srow) * 1024 + cswz * 8;
  const int rswz = (g ^ (c15 & 3)) << 4;
  const int aoff = (wm * 128 + c15) * 64 + rswz;
  const int boff = 65536 + (wn * 64 + c15) * 64 + rswz;

  f32x4 acc[8][4] = {};
  short8 af[8], bf[2];

  auto STAGE_A = [&](int d, int kh, int tk) {
    char* dst = smem + d * 32768 + kh * 16384 + w * 1024;
    const unsigned short* src = a_sr + tk * 64 + kh * 32;
    gl2lds16(src,          dst);
    gl2lds16(src + 131072, dst + 8192);
  };
  auto STAGE_B = [&](int d, int kh, int tk) {
    char* dst = smem + 65536 + d * 32768 + kh * 16384 + w * 1024;
    const unsigned short* src = b_sr + tk * 64 + kh * 32;
    gl2lds16(src,          dst);
    gl2lds16(src + 131072, dst + 8192);
  };
  auto LDA = [&](int d, int ks) {
    const char* base = smem + d * 32768 + ks * 16384 + aoff;
#pragma unroll
    for (int m = 0; m < 8; ++m) af[m] = *(const short8*)(base + m * 1024);
  };
  auto LDB = [&](int d, int ks, int nh) {
    const char* base = smem + d * 32768 + ks * 16384 + boff + nh * 2048;
    bf[0] = *(const short8*)(base);
    bf[1] = *(const short8*)(base + 1024);
  };
  auto MM = [&](int nh) {
    __builtin_amdgcn_s_setprio(1);
#pragma unroll
    for (int n2 = 0; n2 < 2; ++n2)
#pragma unroll
      for (int m = 0; m < 8; ++m)
        acc[m][nh * 2 + n2] =
            __builtin_amdgcn_mfma_f32_16x16x32_bf16(af[m], bf[n2], acc[m][nh * 2 + n2], 0, 0, 0);
    __builtin_amdgcn_s_setprio(0);
  };

  STAGE_A(0, 0, 0); STAGE_B(0, 0, 0); STAGE_A(0, 1, 0); STAGE_B(0, 1, 0);
  vm4();
  bar();

#pragma unroll 1
  for (int tk = 0; tk < 16; tk += 2) {
    const bool more = (tk + 2 < 16);
    LDA(0, 0); LDB(0, 0, 0); STAGE_A(1, 0, tk + 1);          bar(); MM(0); bar();
    LDB(0, 0, 1);            STAGE_B(1, 0, tk + 1);  vm4();  bar(); MM(1); bar();
    LDA(0, 1); LDB(0, 1, 0); STAGE_A(1, 1, tk + 1);          bar(); MM(0); bar();
    LDB(0, 1, 1);            STAGE_B(1, 1, tk + 1);  vm4();  bar(); MM(1); bar();
    LDA(1, 0); LDB(1, 0, 0); if (more) STAGE_A(0, 0, tk + 2);        bar(); MM(0); bar();
    LDB(1, 0, 1);            if (more) STAGE_B(0, 0, tk + 2); vm4(); bar(); MM(1); bar();
    LDA(1, 1); LDB(1, 1, 0); if (more) STAGE_A(0, 1, tk + 2);        bar(); MM(0); bar();
    LDB(1, 1, 1);            if (more) STAGE_B(0, 1, tk + 2); vm4(); bar(); MM(1); bar();
  }

  unsigned short* cl = (unsigned short*)smem;
#pragma unroll
  for (int m = 0; m < 8; ++m)
#pragma unroll
    for (int n = 0; n < 4; ++n)
#pragma unroll
      for (int r = 0; r < 4; ++r)
        cl[(wm * 128 + m * 16 + g * 4 + r) * 256 + wn * 64 + n * 16 + c15] =
            f2b(acc[m][n][r]);
  __syncthreads();
  const int row = tid >> 1, half = tid & 1;
  unsigned short*       dst = C + (m0 + row) * 1024 + n0 + half * 128;
  const unsigned short* sl  = cl + row * 256 + half * 128;
#pragma unroll
  for (int i = 0; i < 16; ++i)
    *(ushort8*)(dst + i * 8) = *(const ushort8*)(sl + i * 8);
}

// ---------------------------------------------------------------------------
// 128x128 2-phase GEMM (round-3 proven) for the small projections (M=512)
// ---------------------------------------------------------------------------
template <bool OUT_F32B>
__global__ __launch_bounds__(256) void gemm_bf16(const unsigned short* __restrict__ A,
                                                 const unsigned short* __restrict__ W,
                                                 void* __restrict__ Cp,
                                                 const float* __restrict__ bias) {
  __shared__ __align__(16) char smem[34816];
  const int tid = threadIdx.x, lane = tid & 63, wv = tid >> 6;
  const int g = lane >> 4, c15 = lane & 15;
  const int wm = wv >> 1, wn = wv & 1;

  const int nwg = gridDim.x;
  const int swz = (blockIdx.x & 7) * (nwg >> 3) + (blockIdx.x >> 3);
  const long m0 = (long)(swz >> 3) * 128;
  const int  n0 = (swz & 7) * 128;

  const int srow = lane >> 2, scol = (lane & 3) * 8;
  const unsigned short* a_src = A + (m0 + srow) * 1024 + scol;
  const unsigned short* b_src = W + (long)(n0 + srow) * 1024 + scol;

  f32x4 acc[4][4] = {};

  auto stage = [&](int buf, int kt) {
    unsigned short* al = (unsigned short*)(smem + buf * 8192);
    unsigned short* bl = (unsigned short*)(smem + 16384 + buf * 8192);
#pragma unroll
    for (int q = 0; q < 2; ++q) {
      const int rbase = q * 64 + wv * 16;
      gl2lds16(a_src + (long)rbase * 1024 + kt * 32, al + rbase * 32);
      gl2lds16(b_src + (long)rbase * 1024 + kt * 32, bl + rbase * 32);
    }
  };

  stage(0, 0);
  __syncthreads();

  int cur = 0;
  for (int kt = 0; kt < 32; ++kt) {
    if (kt + 1 < 32) stage(cur ^ 1, kt + 1);
    const unsigned short* al = (const unsigned short*)(smem + cur * 8192);
    const unsigned short* bl = (const unsigned short*)(smem + 16384 + cur * 8192);
    short8 af[4];
#pragma unroll
    for (int m = 0; m < 4; ++m)
      af[m] = *(const short8*)&al[(wm * 64 + m * 16 + c15) * 32 + g * 8];
#pragma unroll
    for (int n = 0; n < 4; ++n) {
      short8 b8 = *(const short8*)&bl[(wn * 64 + n * 16 + c15) * 32 + g * 8];
#pragma unroll
      for (int m = 0; m < 4; ++m)
        acc[m][n] = __builtin_amdgcn_mfma_f32_16x16x32_bf16(af[m], b8, acc[m][n], 0, 0, 0);
    }
    __syncthreads();
    cur ^= 1;
  }

  if constexpr (OUT_F32B) {
    float* Cf = (float*)Cp;
#pragma unroll
    for (int m = 0; m < 4; ++m)
#pragma unroll
      for (int n = 0; n < 4; ++n)
#pragma unroll
        for (int r = 0; r < 4; ++r) {
          long row = m0 + wm * 64 + m * 16 + g * 4 + r;
          int  col = n0 + wn * 64 + n * 16 + c15;
          Cf[row * 1024 + col] = acc[m][n][r] + bias[col];
        }
  } else {
    unsigned short* c_lds = (unsigned short*)smem;
#pragma unroll
    for (int m = 0; m < 4; ++m)
#pragma unroll
      for (int n = 0; n < 4; ++n)
#pragma unroll
        for (int r = 0; r < 4; ++r)
          c_lds[(wm * 64 + m * 16 + g * 4 + r) * 132 + wn * 64 + n * 16 + c15] =
              f2b(acc[m][n][r]);
    __syncthreads();
    unsigned short* Cb = (unsigned short*)Cp;
    const int row = tid >> 1, half = tid & 1;
    unsigned short*       dst = Cb + (m0 + row) * 1024 + n0 + half * 64;
    const unsigned short* sl  = &c_lds[row * 132 + half * 64];
#pragma unroll
    for (int i = 0; i < 8; ++i)
      *(ushort8*)(dst + i * 8) = *(const ushort8*)(sl + i * 8);
  }
}

// ---------------------------------------------------------------------------
// Attention pass 1 (L-split x4): partial rowsums over 1024 keys per block.
// ---------------------------------------------------------------------------
__global__ __launch_bounds__(512) void attn_pass1(const unsigned short* __restrict__ q_b,
                                                  const unsigned short* __restrict__ k_b,
                                                  float* __restrict__ rs_part) {
  __shared__ unsigned short q_lds[64][72];
  __shared__ unsigned short k_lds[128][72];
  __shared__ float rs_lds[8][64];
  const int bh = blockIdx.x >> 2, ch = blockIdx.x & 3;
  const int b = bh >> 4, h = bh & 15;
  const int tid = threadIdx.x;
  const int w = tid >> 6, lane = tid & 63;
  const int g = lane >> 4, c15 = lane & 15;

  {
    int slot = tid >> 3, cc = (tid & 7) * 8;
    *(ushort8*)&q_lds[slot][cc] =
        *(const ushort8*)(q_b + (long)(b * 64 + slot) * 1024 + h * 64 + cc);
  }

  float rs[4][4] = {};
  const long kbase = (long)b * L_ * D_ + h * 64;
  const int  sl = tid >> 2, sc = (tid & 3) * 16;

  for (int it = ch * 8; it < ch * 8 + 8; ++it) {
    const int l0 = it * 128;
    ushort8 k0 = *(const ushort8*)(k_b + kbase + (long)(l0 + sl) * 1024 + sc);
    ushort8 k1 = *(const ushort8*)(k_b + kbase + (long)(l0 + sl) * 1024 + sc + 8);
    __syncthreads();
    *(ushort8*)&k_lds[sl][sc]     = k0;
    *(ushort8*)&k_lds[sl][sc + 8] = k1;
    __syncthreads();

    f32x4 s[4] = {};
#pragma unroll
    for (int ks = 0; ks < 2; ++ks) {
      short8 bf = *(const short8*)&k_lds[w * 16 + c15][ks * 32 + g * 8];
#pragma unroll
      for (int m = 0; m < 4; ++m) {
        short8 af = *(const short8*)&q_lds[m * 16 + c15][ks * 32 + g * 8];
        s[m] = __builtin_amdgcn_mfma_f32_16x16x32_bf16(af, bf, s[m], 0, 0, 0);
      }
    }
    float mx = -1e30f;
#pragma unroll
    for (int m = 0; m < 4; ++m)
#pragma unroll
      for (int r = 0; r < 4; ++r) mx = fmaxf(mx, s[m][r]);
    mx = fmaxf(mx, __shfl_xor(mx, 16));
    mx = fmaxf(mx, __shfl_xor(mx, 32));
    float sum = 0.f, p[4][4];
#pragma unroll
    for (int m = 0; m < 4; ++m)
#pragma unroll
      for (int r = 0; r < 4; ++r) { p[m][r] = __expf((s[m][r] - mx) * SCALE_); sum += p[m][r]; }
    sum += __shfl_xor(sum, 16);
    sum += __shfl_xor(sum, 32);
    float rinv = 1.0f / sum;
#pragma unroll
    for (int m = 0; m < 4; ++m)
#pragma unroll
      for (int r = 0; r < 4; ++r) rs[m][r] += p[m][r] * rinv;
  }
#pragma unroll
  for (int m = 0; m < 4; ++m)
#pragma unroll
    for (int r = 0; r < 4; ++r) {
      float v = rs[m][r];
      v += __shfl_xor(v, 1); v += __shfl_xor(v, 2);
      v += __shfl_xor(v, 4); v += __shfl_xor(v, 8);
      if (c15 == 0) rs_lds[w][m * 16 + g * 4 + r] = v;
    }
  __syncthreads();
  if (tid < 64) {
    float t = 0.f;
#pragma unroll
    for (int w2 = 0; w2 < 8; ++w2) t += rs_lds[w2][tid];
    rs_part[(bh * 4 + ch) * 64 + tid] = t;
  }
}

// ---------------------------------------------------------------------------
// Attention pass 2 (L-split x4): recompute softmax, scale, write attn fp32,
// PV partial -> op_part fp32.
// ---------------------------------------------------------------------------
__global__ __launch_bounds__(512) void attn_pass2(const unsigned short* __restrict__ q_b,
                                                  const unsigned short* __restrict__ k_b,
                                                  const unsigned short* __restrict__ v_b,
                                                  const float* __restrict__ rs_part,
                                                  float* __restrict__ attn,
                                                  float* __restrict__ op_part) {
  __shared__ unsigned short q_lds[64][72];
  __shared__ unsigned short k_lds[128][72];
  __shared__ unsigned short vt_lds[64][136];
  __shared__ unsigned short pt_lds[64][136];
  const int bh = blockIdx.x >> 2, ch = blockIdx.x & 3;
  const int b = bh >> 4, h = bh & 15;
  const int tid = threadIdx.x;
  const int w = tid >> 6, lane = tid & 63;
  const int g = lane >> 4, c15 = lane & 15;

  {
    int slot = tid >> 3, cc = (tid & 7) * 8;
    *(ushort8*)&q_lds[slot][cc] =
        *(const ushort8*)(q_b + (long)(b * 64 + slot) * 1024 + h * 64 + cc);
  }

  float inv_r[4][4];
#pragma unroll
  for (int m = 0; m < 4; ++m)
#pragma unroll
    for (int r = 0; r < 4; ++r) {
      int slot = m * 16 + g * 4 + r;
      float s = 0.f;
#pragma unroll
      for (int c = 0; c < 4; ++c) s += rs_part[(bh * 4 + c) * 64 + slot];
      inv_r[m][r] = 1.0f / (s + 1e-8f);
    }

  f32x4 oacc[2] = {};
  const int m_pv = w >> 1, n_pv0 = (w & 1) * 2;
  float* attn_base = attn + (long)bh * KS_ * L_;
  const long base_bld = (long)b * L_ * D_ + h * 64;
  const int  sl = tid >> 2, sc = (tid & 3) * 16;

  for (int it = ch * 8; it < ch * 8 + 8; ++it) {
    const int l0 = it * 128;
    ushort8 k0 = *(const ushort8*)(k_b + base_bld + (long)(l0 + sl) * 1024 + sc);
    ushort8 k1 = *(const ushort8*)(k_b + base_bld + (long)(l0 + sl) * 1024 + sc + 8);
    ushort8 v0 = *(const ushort8*)(v_b + base_bld + (long)(l0 + sl) * 1024 + sc);
    ushort8 v1 = *(const ushort8*)(v_b + base_bld + (long)(l0 + sl) * 1024 + sc + 8);
    __syncthreads();
    *(ushort8*)&k_lds[sl][sc]     = k0;
    *(ushort8*)&k_lds[sl][sc + 8] = k1;
#pragma unroll
    for (int j = 0; j < 8; ++j) {
      vt_lds[sc + j][sl]     = v0[j];
      vt_lds[sc + 8 + j][sl] = v1[j];
    }
    __syncthreads();

    f32x4 s[4] = {};
#pragma unroll
    for (int ks = 0; ks < 2; ++ks) {
      short8 bf = *(const short8*)&k_lds[w * 16 + c15][ks * 32 + g * 8];
#pragma unroll
      for (int m = 0; m < 4; ++m) {
        short8 af = *(const short8*)&q_lds[m * 16 + c15][ks * 32 + g * 8];
        s[m] = __builtin_amdgcn_mfma_f32_16x16x32_bf16(af, bf, s[m], 0, 0, 0);
      }
    }
    float mx = -1e30f;
#pragma unroll
    for (int m = 0; m < 4; ++m)
#pragma unroll
      for (int r = 0; r < 4; ++r) mx = fmaxf(mx, s[m][r]);
    mx = fmaxf(mx, __shfl_xor(mx, 16));
    mx = fmaxf(mx, __shfl_xor(mx, 32));
    float sum = 0.f, p[4][4];
#pragma unroll
    for (int m = 0; m < 4; ++m)
#pragma unroll
      for (int r = 0; r < 4; ++r) { p[m][r] = __expf((s[m][r] - mx) * SCALE_); sum += p[m][r]; }
    sum += __shfl_xor(sum, 16);
    sum += __shfl_xor(sum, 32);
    float rinv = 1.0f / sum;

    const int lloc = w * 16 + c15;
#pragma unroll
    for (int m = 0; m < 4; ++m)
#pragma unroll
      for (int r = 0; r < 4; ++r) {
        float ps = p[m][r] * rinv * inv_r[m][r];
        attn_base[(long)(m * 16 + g * 4 + r) * L_ + l0 + lloc] = ps;
        pt_lds[m * 16 + g * 4 + r][lloc] = f2b(ps);
      }
    __syncthreads();

#pragma unroll
    for (int ks = 0; ks < 4; ++ks) {
      short8 pa = *(const short8*)&pt_lds[m_pv * 16 + c15][ks * 32 + g * 8];
#pragma unroll
      for (int n2 = 0; n2 < 2; ++n2) {
        short8 vb = *(const short8*)&vt_lds[(n_pv0 + n2) * 16 + c15][ks * 32 + g * 8];
        oacc[n2] = __builtin_amdgcn_mfma_f32_16x16x32_bf16(pa, vb, oacc[n2], 0, 0, 0);
      }
    }
  }

#pragma unroll
  for (int n2 = 0; n2 < 2; ++n2)
#pragma unroll
    for (int r = 0; r < 4; ++r) {
      int slot = m_pv * 16 + g * 4 + r;
      int c    = (n_pv0 + n2) * 16 + c15;
      op_part[((long)(bh * 4 + ch) * 64 + slot) * 64 + c] = oacc[n2][r];
    }
}

// ---------------------------------------------------------------------------
// Reduce PV chunk-partials -> oh bf16 [512][1024]
// ---------------------------------------------------------------------------
__global__ __launch_bounds__(256) void oh_red(const float* __restrict__ op_part,
                                              unsigned short* __restrict__ oh) {
  int i = blockIdx.x * 256 + threadIdx.x;
  int c = i & 63, slot = (i >> 6) & 63, bh = i >> 12;
  float s = 0.f;
#pragma unroll
  for (int ch = 0; ch < 4; ++ch)
    s += op_part[((long)(bh * 4 + ch) * 64 + slot) * 64 + c];
  int b = bh >> 4, h = bh & 15;
  oh[(long)(b * 64 + slot) * 1024 + h * 64 + c] = f2b(s);
}

// ---------------------------------------------------------------------------
extern "C" void kernel_launch(void* const* d_in, const int* in_sizes, int n_in,
                              void* d_out, int out_size, void* d_ws, size_t ws_size,
                              hipStream_t stream) {
  (void)in_sizes; (void)n_in; (void)out_size; (void)ws_size;
  const float* query = (const float*)d_in[0];
  const float* key   = (const float*)d_in[1];
  const float* value = (const float*)d_in[2];
  const float* Wq    = (const float*)d_in[3];
  const float* Wk    = (const float*)d_in[4];
  const float* Wv    = (const float*)d_in[5];
  const float* Wo    = (const float*)d_in[6];
  const float* bo    = (const float*)d_in[7];

  char* ws = (char*)d_ws;
  unsigned short* w_all   = (unsigned short*)ws;                        // 8 MB
  unsigned short* wq_b    = w_all;
  unsigned short* wk_b    = w_all + (1u << 20);
  unsigned short* wv_b    = w_all + (2u << 20);
  unsigned short* wo_b    = w_all + (3u << 20);
  unsigned short* qin_b   = (unsigned short*)(ws + ((size_t)8  << 20)); // 1 MB
  unsigned short* q_b     = (unsigned short*)(ws + ((size_t)9  << 20)); // 1 MB
  unsigned short* oh_b    = (unsigned short*)(ws + ((size_t)10 << 20)); // 1 MB
  float*          rs_part = (float*)         (ws + ((size_t)11 << 20)); // 128 KB
  float*          op_part = (float*)         (ws + ((size_t)12 << 20)); // 8 MB
  unsigned short* k_b     = (unsigned short*)(ws + ((size_t)20 << 20)); // 64 MB
  unsigned short* v_b     = (unsigned short*)(ws + ((size_t)84 << 20)); // 64 MB

  float* out  = (float*)d_out;
  float* attn = out + (size_t)B_ * KS_ * D_;

  // converted K/V inputs live in the not-yet-written attn output region
  // (consumed by the K/V projections, which run before attn_pass2 writes it)
  unsigned short* kin_b = (unsigned short*)attn;
  unsigned short* vin_b = (unsigned short*)attn + ((size_t)32 << 20);

  wcvt<<<4608, 256, 0, stream>>>(Wq, Wk, Wv, Wo, query, w_all, qin_b);
  cvt1<<<4096, 256, 0, stream>>>(key,   kin_b, 4194304);
  cvt1<<<4096, 256, 0, stream>>>(value, vin_b, 4194304);

  gemm_bf16<false><<<32, 256, 0, stream>>>(qin_b, wq_b, q_b, nullptr);
  gemm256<<<512, 512, 0, stream>>>(kin_b, wk_b, k_b);
  gemm256<<<512, 512, 0, stream>>>(vin_b, wv_b, v_b);

  attn_pass1<<<512, 512, 0, stream>>>(q_b, k_b, rs_part);
  attn_pass2<<<512, 512, 0, stream>>>(q_b, k_b, v_b, rs_part, attn, op_part);
  oh_red<<<2048, 256, 0, stream>>>(op_part, oh_b);

  gemm_bf16<true><<<32, 256, 0, stream>>>(oh_b, wo_b, out, bo);
}

// Round 11
// 370.087 us; speedup vs baseline: 1.5655x; 1.0313x over previous
//
#include <hip/hip_runtime.h>
#include <hip/hip_bf16.h>

#define B_   8
#define KS_  64
#define L_   4096
#define D_   1024
#define H_   16
#define HD_  64
#define SCALE_ 0.125f

typedef __attribute__((ext_vector_type(8))) short short8;
typedef __attribute__((ext_vector_type(8))) unsigned short ushort8;
typedef __attribute__((ext_vector_type(4))) unsigned short ushort4v;
typedef __attribute__((ext_vector_type(4))) float f32x4;

__device__ __forceinline__ unsigned short f2b(float f) {
  union { float f; unsigned u; } v; v.f = f;
  unsigned r = v.u + 0x7fffu + ((v.u >> 16) & 1u);
  return (unsigned short)(r >> 16);
}

typedef const __attribute__((address_space(1))) void gas_void;
typedef __attribute__((address_space(3))) void las_void;
__device__ __forceinline__ void gl2lds16(const void* g, void* l) {
  __builtin_amdgcn_global_load_lds((gas_void*)g, (las_void*)l, 16, 0, 0);
}

__device__ __forceinline__ void bar() {           // raw barrier: no vmcnt drain
  asm volatile("" ::: "memory");
  __builtin_amdgcn_s_barrier();
  asm volatile("" ::: "memory");
}
__device__ __forceinline__ void vm4() {           // counted vmcnt (T4)
  asm volatile("s_waitcnt vmcnt(4)" ::: "memory");
}

// ---------------------------------------------------------------------------
// Convert: 4 x [1024x1024] weights + query [512x1024] fp32 -> bf16 in ws
// ---------------------------------------------------------------------------
__global__ __launch_bounds__(256) void wcvt(const float* __restrict__ wq,
                                            const float* __restrict__ wk,
                                            const float* __restrict__ wv,
                                            const float* __restrict__ wo,
                                            const float* __restrict__ query,
                                            unsigned short* __restrict__ wout,
                                            unsigned short* __restrict__ qout) {
  int i = blockIdx.x * 256 + threadIdx.x;        // 1,179,648 float4 units
  const float* src;
  unsigned short* dst;
  int off;
  if (i < (4 << 18)) {
    int seg = i >> 18;
    off = (i & 0x3ffff) << 2;
    src = (seg == 0) ? wq : (seg == 1) ? wk : (seg == 2) ? wv : wo;
    dst = wout + ((size_t)seg << 20);
  } else {
    off = (i - (4 << 18)) << 2;                  // 0 .. 524287
    src = query;
    dst = qout;
  }
  f32x4 v = *(const f32x4*)(src + off);
  ushort4v o;
#pragma unroll
  for (int j = 0; j < 4; ++j) o[j] = f2b(v[j]);
  *(ushort4v*)(dst + off) = o;
}

// ---------------------------------------------------------------------------
// Single-tensor streaming convert fp32 -> bf16 (1 read + 1 write stream)
// ---------------------------------------------------------------------------
__global__ __launch_bounds__(256) void cvt1(const float* __restrict__ src,
                                            unsigned short* __restrict__ dst,
                                            int nunits) {
  const int stride = gridDim.x * 256;
  for (int i = blockIdx.x * 256 + threadIdx.x; i < nunits; i += stride) {
    const f32x4* p = (const f32x4*)(src + (size_t)i * 8);
    f32x4 a = __builtin_nontemporal_load(p);
    f32x4 b = __builtin_nontemporal_load(p + 1);
    ushort8 o;
#pragma unroll
    for (int j = 0; j < 4; ++j) { o[j] = f2b(a[j]); o[j + 4] = f2b(b[j]); }
    *(ushort8*)(dst + (size_t)i * 8) = o;
  }
}

// ---------------------------------------------------------------------------
// 256x256 8-phase GEMM (T2+T3+T4+T5): C[M][1024] = A(bf16) @ W(bf16)^T
//  Round-6 structure with CORRECTED T2 swizzle: chunk ^= (row>>1)&3.
//  Derivation: 64B rows -> bank-quad position of chunk p at row r is
//  16*(r&1) + 4p (mod 32). Old "chunk^=row&3" left only 4 distinct
//  positions per 8-lane pass (lanes c15 and c15+4 collided -> 2x passes,
//  11.3M conflicts). With (row>>1)&3 an 8-lane pass covers all 8 quads
//  {0,16,4,20,8,24,12,28}. Both-sides (rule #21): staging source chunk
//  = (lane&3)^((lane>>3)&3) (since (srow>>1)&3 = (lane>>3)&3, carry-free);
//  read chunk = g^((c15>>1)&3) (wm*128/m*16/wn*64 all ≡ 0 mod 4 after >>1).
// ---------------------------------------------------------------------------
__global__ __launch_bounds__(512, 2) void gemm256(const unsigned short* __restrict__ A,
                                                  const unsigned short* __restrict__ W,
                                                  unsigned short* __restrict__ C) {
  __shared__ __align__(16) char smem[131072];
  const int tid = threadIdx.x, lane = tid & 63, w = tid >> 6;
  const int g = lane >> 4, c15 = lane & 15;
  const int wm = w >> 2, wn = w & 3;

  const int swz = (blockIdx.x & 7) * 64 + (blockIdx.x >> 3);
  const long m0 = (long)(swz >> 2) * 256;
  const int  n0 = (swz & 3) * 256;

  const int srow = w * 16 + (lane >> 2);
  const int cswz = (lane & 3) ^ ((lane >> 3) & 3);        // (srow>>1)&3
  const unsigned short* a_sr = A + (m0 + srow) * 1024 + cswz * 8;
  const unsigned short* b_sr = W + (long)(n0 + srow) * 1024 + cswz * 8;
  const int rswz = (g ^ ((c15 >> 1) & 3)) << 4;           // (row>>1)&3
  const int aoff = (wm * 128 + c15) * 64 + rswz;
  const int boff = 65536 + (wn * 64 + c15) * 64 + rswz;

  f32x4 acc[8][4] = {};
  short8 af[8], bf[2];

  auto STAGE_A = [&](int d, int kh, int tk) {
    char* dst = smem + d * 32768 + kh * 16384 + w * 1024;
    const unsigned short* src = a_sr + tk * 64 + kh * 32;
    gl2lds16(src,          dst);
    gl2lds16(src + 131072, dst + 8192);                   // +128 rows: swz same
  };
  auto STAGE_B = [&](int d, int kh, int tk) {
    char* dst = smem + 65536 + d * 32768 + kh * 16384 + w * 1024;
    const unsigned short* src = b_sr + tk * 64 + kh * 32;
    gl2lds16(src,          dst);
    gl2lds16(src + 131072, dst + 8192);
  };
  auto LDA = [&](int d, int ks) {
    const char* base = smem + d * 32768 + ks * 16384 + aoff;
#pragma unroll
    for (int m = 0; m < 8; ++m) af[m] = *(const short8*)(base + m * 1024);
  };
  auto LDB = [&](int d, int ks, int nh) {
    const char* base = smem + d * 32768 + ks * 16384 + boff + nh * 2048;
    bf[0] = *(const short8*)(base);
    bf[1] = *(const short8*)(base + 1024);
  };
  auto MM = [&](int nh) {
    __builtin_amdgcn_s_setprio(1);
#pragma unroll
    for (int n2 = 0; n2 < 2; ++n2)
#pragma unroll
      for (int m = 0; m < 8; ++m)
        acc[m][nh * 2 + n2] =
            __builtin_amdgcn_mfma_f32_16x16x32_bf16(af[m], bf[n2], acc[m][nh * 2 + n2], 0, 0, 0);
    __builtin_amdgcn_s_setprio(0);
  };

  STAGE_A(0, 0, 0); STAGE_B(0, 0, 0); STAGE_A(0, 1, 0); STAGE_B(0, 1, 0);
  vm4();
  bar();

#pragma unroll 1
  for (int tk = 0; tk < 16; tk += 2) {
    const bool more = (tk + 2 < 16);
    LDA(0, 0); LDB(0, 0, 0); STAGE_A(1, 0, tk + 1);          bar(); MM(0); bar();
    LDB(0, 0, 1);            STAGE_B(1, 0, tk + 1);  vm4();  bar(); MM(1); bar();
    LDA(0, 1); LDB(0, 1, 0); STAGE_A(1, 1, tk + 1);          bar(); MM(0); bar();
    LDB(0, 1, 1);            STAGE_B(1, 1, tk + 1);  vm4();  bar(); MM(1); bar();
    LDA(1, 0); LDB(1, 0, 0); if (more) STAGE_A(0, 0, tk + 2);        bar(); MM(0); bar();
    LDB(1, 0, 1);            if (more) STAGE_B(0, 0, tk + 2); vm4(); bar(); MM(1); bar();
    LDA(1, 1); LDB(1, 1, 0); if (more) STAGE_A(0, 1, tk + 2);        bar(); MM(0); bar();
    LDB(1, 1, 1);            if (more) STAGE_B(0, 1, tk + 2); vm4(); bar(); MM(1); bar();
  }

  unsigned short* cl = (unsigned short*)smem;
#pragma unroll
  for (int m = 0; m < 8; ++m)
#pragma unroll
    for (int n = 0; n < 4; ++n)
#pragma unroll
      for (int r = 0; r < 4; ++r)
        cl[(wm * 128 + m * 16 + g * 4 + r) * 256 + wn * 64 + n * 16 + c15] =
            f2b(acc[m][n][r]);
  __syncthreads();
  const int row = tid >> 1, half = tid & 1;
  unsigned short*       dst = C + (m0 + row) * 1024 + n0 + half * 128;
  const unsigned short* sl  = cl + row * 256 + half * 128;
#pragma unroll
  for (int i = 0; i < 16; ++i)
    *(ushort8*)(dst + i * 8) = *(const ushort8*)(sl + i * 8);
}

// ---------------------------------------------------------------------------
// 128x128 2-phase GEMM (round-3 proven) for the small projections (M=512)
// ---------------------------------------------------------------------------
template <bool OUT_F32B>
__global__ __launch_bounds__(256) void gemm_bf16(const unsigned short* __restrict__ A,
                                                 const unsigned short* __restrict__ W,
                                                 void* __restrict__ Cp,
                                                 const float* __restrict__ bias) {
  __shared__ __align__(16) char smem[34816];
  const int tid = threadIdx.x, lane = tid & 63, wv = tid >> 6;
  const int g = lane >> 4, c15 = lane & 15;
  const int wm = wv >> 1, wn = wv & 1;

  const int nwg = gridDim.x;
  const int swz = (blockIdx.x & 7) * (nwg >> 3) + (blockIdx.x >> 3);
  const long m0 = (long)(swz >> 3) * 128;
  const int  n0 = (swz & 7) * 128;

  const int srow = lane >> 2, scol = (lane & 3) * 8;
  const unsigned short* a_src = A + (m0 + srow) * 1024 + scol;
  const unsigned short* b_src = W + (long)(n0 + srow) * 1024 + scol;

  f32x4 acc[4][4] = {};

  auto stage = [&](int buf, int kt) {
    unsigned short* al = (unsigned short*)(smem + buf * 8192);
    unsigned short* bl = (unsigned short*)(smem + 16384 + buf * 8192);
#pragma unroll
    for (int q = 0; q < 2; ++q) {
      const int rbase = q * 64 + wv * 16;
      gl2lds16(a_src + (long)rbase * 1024 + kt * 32, al + rbase * 32);
      gl2lds16(b_src + (long)rbase * 1024 + kt * 32, bl + rbase * 32);
    }
  };

  stage(0, 0);
  __syncthreads();

  int cur = 0;
  for (int kt = 0; kt < 32; ++kt) {
    if (kt + 1 < 32) stage(cur ^ 1, kt + 1);
    const unsigned short* al = (const unsigned short*)(smem + cur * 8192);
    const unsigned short* bl = (const unsigned short*)(smem + 16384 + cur * 8192);
    short8 af[4];
#pragma unroll
    for (int m = 0; m < 4; ++m)
      af[m] = *(const short8*)&al[(wm * 64 + m * 16 + c15) * 32 + g * 8];
#pragma unroll
    for (int n = 0; n < 4; ++n) {
      short8 b8 = *(const short8*)&bl[(wn * 64 + n * 16 + c15) * 32 + g * 8];
#pragma unroll
      for (int m = 0; m < 4; ++m)
        acc[m][n] = __builtin_amdgcn_mfma_f32_16x16x32_bf16(af[m], b8, acc[m][n], 0, 0, 0);
    }
    __syncthreads();
    cur ^= 1;
  }

  if constexpr (OUT_F32B) {
    float* Cf = (float*)Cp;
#pragma unroll
    for (int m = 0; m < 4; ++m)
#pragma unroll
      for (int n = 0; n < 4; ++n)
#pragma unroll
        for (int r = 0; r < 4; ++r) {
          long row = m0 + wm * 64 + m * 16 + g * 4 + r;
          int  col = n0 + wn * 64 + n * 16 + c15;
          Cf[row * 1024 + col] = acc[m][n][r] + bias[col];
        }
  } else {
    unsigned short* c_lds = (unsigned short*)smem;
#pragma unroll
    for (int m = 0; m < 4; ++m)
#pragma unroll
      for (int n = 0; n < 4; ++n)
#pragma unroll
        for (int r = 0; r < 4; ++r)
          c_lds[(wm * 64 + m * 16 + g * 4 + r) * 132 + wn * 64 + n * 16 + c15] =
              f2b(acc[m][n][r]);
    __syncthreads();
    unsigned short* Cb = (unsigned short*)Cp;
    const int row = tid >> 1, half = tid & 1;
    unsigned short*       dst = Cb + (m0 + row) * 1024 + n0 + half * 64;
    const unsigned short* sl  = &c_lds[row * 132 + half * 64];
#pragma unroll
    for (int i = 0; i < 8; ++i)
      *(ushort8*)(dst + i * 8) = *(const ushort8*)(sl + i * 8);
  }
}

// ---------------------------------------------------------------------------
// Attention pass 1 (L-split x4): partial rowsums over 1024 keys per block.
// ---------------------------------------------------------------------------
__global__ __launch_bounds__(512) void attn_pass1(const unsigned short* __restrict__ q_b,
                                                  const unsigned short* __restrict__ k_b,
                                                  float* __restrict__ rs_part) {
  __shared__ unsigned short q_lds[64][72];
  __shared__ unsigned short k_lds[128][72];
  __shared__ float rs_lds[8][64];
  const int bh = blockIdx.x >> 2, ch = blockIdx.x & 3;
  const int b = bh >> 4, h = bh & 15;
  const int tid = threadIdx.x;
  const int w = tid >> 6, lane = tid & 63;
  const int g = lane >> 4, c15 = lane & 15;

  {
    int slot = tid >> 3, cc = (tid & 7) * 8;
    *(ushort8*)&q_lds[slot][cc] =
        *(const ushort8*)(q_b + (long)(b * 64 + slot) * 1024 + h * 64 + cc);
  }

  float rs[4][4] = {};
  const long kbase = (long)b * L_ * D_ + h * 64;
  const int  sl = tid >> 2, sc = (tid & 3) * 16;

  for (int it = ch * 8; it < ch * 8 + 8; ++it) {
    const int l0 = it * 128;
    ushort8 k0 = *(const ushort8*)(k_b + kbase + (long)(l0 + sl) * 1024 + sc);
    ushort8 k1 = *(const ushort8*)(k_b + kbase + (long)(l0 + sl) * 1024 + sc + 8);
    __syncthreads();
    *(ushort8*)&k_lds[sl][sc]     = k0;
    *(ushort8*)&k_lds[sl][sc + 8] = k1;
    __syncthreads();

    f32x4 s[4] = {};
#pragma unroll
    for (int ks = 0; ks < 2; ++ks) {
      short8 bf = *(const short8*)&k_lds[w * 16 + c15][ks * 32 + g * 8];
#pragma unroll
      for (int m = 0; m < 4; ++m) {
        short8 af = *(const short8*)&q_lds[m * 16 + c15][ks * 32 + g * 8];
        s[m] = __builtin_amdgcn_mfma_f32_16x16x32_bf16(af, bf, s[m], 0, 0, 0);
      }
    }
    float mx = -1e30f;
#pragma unroll
    for (int m = 0; m < 4; ++m)
#pragma unroll
      for (int r = 0; r < 4; ++r) mx = fmaxf(mx, s[m][r]);
    mx = fmaxf(mx, __shfl_xor(mx, 16));
    mx = fmaxf(mx, __shfl_xor(mx, 32));
    float sum = 0.f, p[4][4];
#pragma unroll
    for (int m = 0; m < 4; ++m)
#pragma unroll
      for (int r = 0; r < 4; ++r) { p[m][r] = __expf((s[m][r] - mx) * SCALE_); sum += p[m][r]; }
    sum += __shfl_xor(sum, 16);
    sum += __shfl_xor(sum, 32);
    float rinv = 1.0f / sum;
#pragma unroll
    for (int m = 0; m < 4; ++m)
#pragma unroll
      for (int r = 0; r < 4; ++r) rs[m][r] += p[m][r] * rinv;
  }
#pragma unroll
  for (int m = 0; m < 4; ++m)
#pragma unroll
    for (int r = 0; r < 4; ++r) {
      float v = rs[m][r];
      v += __shfl_xor(v, 1); v += __shfl_xor(v, 2);
      v += __shfl_xor(v, 4); v += __shfl_xor(v, 8);
      if (c15 == 0) rs_lds[w][m * 16 + g * 4 + r] = v;
    }
  __syncthreads();
  if (tid < 64) {
    float t = 0.f;
#pragma unroll
    for (int w2 = 0; w2 < 8; ++w2) t += rs_lds[w2][tid];
    rs_part[(bh * 4 + ch) * 64 + tid] = t;
  }
}

// ---------------------------------------------------------------------------
// Attention pass 2 (L-split x4): recompute softmax, scale, write attn fp32
// (nontemporal: 134 MB single-use stream, keep it out of L2), PV partial.
// ---------------------------------------------------------------------------
__global__ __launch_bounds__(512) void attn_pass2(const unsigned short* __restrict__ q_b,
                                                  const unsigned short* __restrict__ k_b,
                                                  const unsigned short* __restrict__ v_b,
                                                  const float* __restrict__ rs_part,
                                                  float* __restrict__ attn,
                                                  float* __restrict__ op_part) {
  __shared__ unsigned short q_lds[64][72];
  __shared__ unsigned short k_lds[128][72];
  __shared__ unsigned short vt_lds[64][136];
  __shared__ unsigned short pt_lds[64][136];
  const int bh = blockIdx.x >> 2, ch = blockIdx.x & 3;
  const int b = bh >> 4, h = bh & 15;
  const int tid = threadIdx.x;
  const int w = tid >> 6, lane = tid & 63;
  const int g = lane >> 4, c15 = lane & 15;

  {
    int slot = tid >> 3, cc = (tid & 7) * 8;
    *(ushort8*)&q_lds[slot][cc] =
        *(const ushort8*)(q_b + (long)(b * 64 + slot) * 1024 + h * 64 + cc);
  }

  float inv_r[4][4];
#pragma unroll
  for (int m = 0; m < 4; ++m)
#pragma unroll
    for (int r = 0; r < 4; ++r) {
      int slot = m * 16 + g * 4 + r;
      float s = 0.f;
#pragma unroll
      for (int c = 0; c < 4; ++c) s += rs_part[(bh * 4 + c) * 64 + slot];
      inv_r[m][r] = 1.0f / (s + 1e-8f);
    }

  f32x4 oacc[2] = {};
  const int m_pv = w >> 1, n_pv0 = (w & 1) * 2;
  float* attn_base = attn + (long)bh * KS_ * L_;
  const long base_bld = (long)b * L_ * D_ + h * 64;
  const int  sl = tid >> 2, sc = (tid & 3) * 16;

  for (int it = ch * 8; it < ch * 8 + 8; ++it) {
    const int l0 = it * 128;
    ushort8 k0 = *(const ushort8*)(k_b + base_bld + (long)(l0 + sl) * 1024 + sc);
    ushort8 k1 = *(const ushort8*)(k_b + base_bld + (long)(l0 + sl) * 1024 + sc + 8);
    ushort8 v0 = *(const ushort8*)(v_b + base_bld + (long)(l0 + sl) * 1024 + sc);
    ushort8 v1 = *(const ushort8*)(v_b + base_bld + (long)(l0 + sl) * 1024 + sc + 8);
    __syncthreads();
    *(ushort8*)&k_lds[sl][sc]     = k0;
    *(ushort8*)&k_lds[sl][sc + 8] = k1;
#pragma unroll
    for (int j = 0; j < 8; ++j) {
      vt_lds[sc + j][sl]     = v0[j];
      vt_lds[sc + 8 + j][sl] = v1[j];
    }
    __syncthreads();

    f32x4 s[4] = {};
#pragma unroll
    for (int ks = 0; ks < 2; ++ks) {
      short8 bf = *(const short8*)&k_lds[w * 16 + c15][ks * 32 + g * 8];
#pragma unroll
      for (int m = 0; m < 4; ++m) {
        short8 af = *(const short8*)&q_lds[m * 16 + c15][ks * 32 + g * 8];
        s[m] = __builtin_amdgcn_mfma_f32_16x16x32_bf16(af, bf, s[m], 0, 0, 0);
      }
    }
    float mx = -1e30f;
#pragma unroll
    for (int m = 0; m < 4; ++m)
#pragma unroll
      for (int r = 0; r < 4; ++r) mx = fmaxf(mx, s[m][r]);
    mx = fmaxf(mx, __shfl_xor(mx, 16));
    mx = fmaxf(mx, __shfl_xor(mx, 32));
    float sum = 0.f, p[4][4];
#pragma unroll
    for (int m = 0; m < 4; ++m)
#pragma unroll
      for (int r = 0; r < 4; ++r) { p[m][r] = __expf((s[m][r] - mx) * SCALE_); sum += p[m][r]; }
    sum += __shfl_xor(sum, 16);
    sum += __shfl_xor(sum, 32);
    float rinv = 1.0f / sum;

    const int lloc = w * 16 + c15;
#pragma unroll
    for (int m = 0; m < 4; ++m)
#pragma unroll
      for (int r = 0; r < 4; ++r) {
        float ps = p[m][r] * rinv * inv_r[m][r];
        __builtin_nontemporal_store(ps,
            &attn_base[(long)(m * 16 + g * 4 + r) * L_ + l0 + lloc]);
        pt_lds[m * 16 + g * 4 + r][lloc] = f2b(ps);
      }
    __syncthreads();

#pragma unroll
    for (int ks = 0; ks < 4; ++ks) {
      short8 pa = *(const short8*)&pt_lds[m_pv * 16 + c15][ks * 32 + g * 8];
#pragma unroll
      for (int n2 = 0; n2 < 2; ++n2) {
        short8 vb = *(const short8*)&vt_lds[(n_pv0 + n2) * 16 + c15][ks * 32 + g * 8];
        oacc[n2] = __builtin_amdgcn_mfma_f32_16x16x32_bf16(pa, vb, oacc[n2], 0, 0, 0);
      }
    }
  }

#pragma unroll
  for (int n2 = 0; n2 < 2; ++n2)
#pragma unroll
    for (int r = 0; r < 4; ++r) {
      int slot = m_pv * 16 + g * 4 + r;
      int c    = (n_pv0 + n2) * 16 + c15;
      op_part[((long)(bh * 4 + ch) * 64 + slot) * 64 + c] = oacc[n2][r];
    }
}

// ---------------------------------------------------------------------------
// Reduce PV chunk-partials -> oh bf16 [512][1024]
// ---------------------------------------------------------------------------
__global__ __launch_bounds__(256) void oh_red(const float* __restrict__ op_part,
                                              unsigned short* __restrict__ oh) {
  int i = blockIdx.x * 256 + threadIdx.x;
  int c = i & 63, slot = (i >> 6) & 63, bh = i >> 12;
  float s = 0.f;
#pragma unroll
  for (int ch = 0; ch < 4; ++ch)
    s += op_part[((long)(bh * 4 + ch) * 64 + slot) * 64 + c];
  int b = bh >> 4, h = bh & 15;
  oh[(long)(b * 64 + slot) * 1024 + h * 64 + c] = f2b(s);
}

// ---------------------------------------------------------------------------
extern "C" void kernel_launch(void* const* d_in, const int* in_sizes, int n_in,
                              void* d_out, int out_size, void* d_ws, size_t ws_size,
                              hipStream_t stream) {
  (void)in_sizes; (void)n_in; (void)out_size; (void)ws_size;
  const float* query = (const float*)d_in[0];
  const float* key   = (const float*)d_in[1];
  const float* value = (const float*)d_in[2];
  const float* Wq    = (const float*)d_in[3];
  const float* Wk    = (const float*)d_in[4];
  const float* Wv    = (const float*)d_in[5];
  const float* Wo    = (const float*)d_in[6];
  const float* bo    = (const float*)d_in[7];

  char* ws = (char*)d_ws;
  unsigned short* w_all   = (unsigned short*)ws;                        // 8 MB
  unsigned short* wq_b    = w_all;
  unsigned short* wk_b    = w_all + (1u << 20);
  unsigned short* wv_b    = w_all + (2u << 20);
  unsigned short* wo_b    = w_all + (3u << 20);
  unsigned short* qin_b   = (unsigned short*)(ws + ((size_t)8  << 20)); // 1 MB
  unsigned short* q_b     = (unsigned short*)(ws + ((size_t)9  << 20)); // 1 MB
  unsigned short* oh_b    = (unsigned short*)(ws + ((size_t)10 << 20)); // 1 MB
  float*          rs_part = (float*)         (ws + ((size_t)11 << 20)); // 128 KB
  float*          op_part = (float*)         (ws + ((size_t)12 << 20)); // 8 MB
  unsigned short* k_b     = (unsigned short*)(ws + ((size_t)20 << 20)); // 64 MB
  unsigned short* v_b     = (unsigned short*)(ws + ((size_t)84 << 20)); // 64 MB

  float* out  = (float*)d_out;
  float* attn = out + (size_t)B_ * KS_ * D_;

  // converted K/V inputs live in the not-yet-written attn output region
  unsigned short* kin_b = (unsigned short*)attn;
  unsigned short* vin_b = (unsigned short*)attn + ((size_t)32 << 20);

  wcvt<<<4608, 256, 0, stream>>>(Wq, Wk, Wv, Wo, query, w_all, qin_b);
  cvt1<<<4096, 256, 0, stream>>>(key,   kin_b, 4194304);
  cvt1<<<4096, 256, 0, stream>>>(value, vin_b, 4194304);

  gemm_bf16<false><<<32, 256, 0, stream>>>(qin_b, wq_b, q_b, nullptr);
  gemm256<<<512, 512, 0, stream>>>(kin_b, wk_b, k_b);
  gemm256<<<512, 512, 0, stream>>>(vin_b, wv_b, v_b);

  attn_pass1<<<512, 512, 0, stream>>>(q_b, k_b, rs_part);
  attn_pass2<<<512, 512, 0, stream>>>(q_b, k_b, v_b, rs_part, attn, op_part);
  oh_red<<<2048, 256, 0, stream>>>(op_part, oh_b);

  gemm_bf16<true><<<32, 256, 0, stream>>>(oh_b, wo_b, out, bo);
}

// Round 12
// 363.307 us; speedup vs baseline: 1.5947x; 1.0187x over previous
//
#include <hip/hip_runtime.h>
#include <hip/hip_bf16.h>

#define B_   8
#define KS_  64
#define L_   4096
#define D_   1024
#define H_   16
#define HD_  64
#define SCALE_ 0.125f

typedef __attribute__((ext_vector_type(8))) short short8;
typedef __attribute__((ext_vector_type(8))) unsigned short ushort8;
typedef __attribute__((ext_vector_type(4))) unsigned short ushort4v;
typedef __attribute__((ext_vector_type(4))) float f32x4;

__device__ __forceinline__ unsigned short f2b(float f) {
  union { float f; unsigned u; } v; v.f = f;
  unsigned r = v.u + 0x7fffu + ((v.u >> 16) & 1u);
  return (unsigned short)(r >> 16);
}

// HW packed fp32->bf16 RTNE (same rounding as f2b; no builtin on gfx950)
__device__ __forceinline__ unsigned cvtpk(float a, float b) {
  unsigned r;
  asm("v_cvt_pk_bf16_f32 %0, %1, %2" : "=v"(r) : "v"(a), "v"(b));
  return r;
}

typedef const __attribute__((address_space(1))) void gas_void;
typedef __attribute__((address_space(3))) void las_void;
__device__ __forceinline__ void gl2lds16(const void* g, void* l) {
  __builtin_amdgcn_global_load_lds((gas_void*)g, (las_void*)l, 16, 0, 0);
}

__device__ __forceinline__ void bar() {           // raw barrier: no vmcnt drain
  asm volatile("" ::: "memory");
  __builtin_amdgcn_s_barrier();
  asm volatile("" ::: "memory");
}
__device__ __forceinline__ void vm0() { asm volatile("s_waitcnt vmcnt(0)" ::: "memory"); }
__device__ __forceinline__ void vm4() { asm volatile("s_waitcnt vmcnt(4)" ::: "memory"); }
__device__ __forceinline__ void vm6() { asm volatile("s_waitcnt vmcnt(6)" ::: "memory"); }

// ---------------------------------------------------------------------------
// Convert: 4 x [1024x1024] weights + query [512x1024] fp32 -> bf16 in ws
// ---------------------------------------------------------------------------
__global__ __launch_bounds__(256) void wcvt(const float* __restrict__ wq,
                                            const float* __restrict__ wk,
                                            const float* __restrict__ wv,
                                            const float* __restrict__ wo,
                                            const float* __restrict__ query,
                                            unsigned short* __restrict__ wout,
                                            unsigned short* __restrict__ qout) {
  int i = blockIdx.x * 256 + threadIdx.x;
  const float* src;
  unsigned short* dst;
  int off;
  if (i < (4 << 18)) {
    int seg = i >> 18;
    off = (i & 0x3ffff) << 2;
    src = (seg == 0) ? wq : (seg == 1) ? wk : (seg == 2) ? wv : wo;
    dst = wout + ((size_t)seg << 20);
  } else {
    off = (i - (4 << 18)) << 2;
    src = query;
    dst = qout;
  }
  f32x4 v = *(const f32x4*)(src + off);
  ushort4v o;
#pragma unroll
  for (int j = 0; j < 4; ++j) o[j] = f2b(v[j]);
  *(ushort4v*)(dst + off) = o;
}

// ---------------------------------------------------------------------------
// Single-tensor streaming convert fp32 -> bf16 (V only this round)
// ---------------------------------------------------------------------------
__global__ __launch_bounds__(256) void cvt1(const float* __restrict__ src,
                                            unsigned short* __restrict__ dst,
                                            int nunits) {
  const int stride = gridDim.x * 256;
  for (int i = blockIdx.x * 256 + threadIdx.x; i < nunits; i += stride) {
    const f32x4* p = (const f32x4*)(src + (size_t)i * 8);
    f32x4 a = __builtin_nontemporal_load(p);
    f32x4 b = __builtin_nontemporal_load(p + 1);
    ushort8 o;
#pragma unroll
    for (int j = 0; j < 4; ++j) { o[j] = f2b(a[j]); o[j + 4] = f2b(b[j]); }
    *(ushort8*)(dst + (size_t)i * 8) = o;
  }
}

// ---------------------------------------------------------------------------
// gemm256f32: C[M][1024](bf16) = A[M][1024](fp32) @ W^T(bf16)  — fused cvt.
//  BM=BN=256, BK=32 (32 K-tiles), 8 waves, 3-BUFFER LDS (prefetch dist 2):
//    A fp32 [256][32] = 32KB x3 @0 ; B bf16 [256][32] = 16KB x3 @98304.
//  Both operands via gl2lds (NO reg staging -> no arch-VGPR pressure; the
//  512-thr block caps arch VGPRs at 128 hard, acc lives in AGPRs).
//  fp32->bf16 happens at frag read: 2x ds_read_b128 + 4x cvtpk per frag.
//  A swizzle: 128B rows = 8 x 16B chunks, all rows start bank 0 ->
//    chunk ^= row&7 (both sides: fetch-col pre-swizzle + read-side XOR).
//  B swizzle: 64B rows -> chunk ^= (row>>1)&3 (round-11 verified).
//  Schedule: 2 phases/tile {ph1: LDA+cvt, LDB n01, stage 3 of T(t+2);
//  bar MM01 bar | ph2: LDB n23, stage 3 more, vmcnt(6); bar MM23 bar}.
//  vmcnt ledger: entering tile t, outstanding = T(t+1)'s 6 loads (issued
//  during t-1). ph1/ph2 issue T(t+2)'s 6 -> vm6 at ph2 end retires T(t+1)
//  (consumed at t+1.ph1, ~4 phases after issue). Tail: vm0 at tile 30.
// ---------------------------------------------------------------------------
__global__ __launch_bounds__(512) void gemm256f32(const float* __restrict__ A,
                                                  const unsigned short* __restrict__ W,
                                                  unsigned short* __restrict__ C) {
  __shared__ __align__(16) char smem[147456];
  const int tid = threadIdx.x, lane = tid & 63, w = tid >> 6;
  const int g = lane >> 4, c15 = lane & 15;
  const int wm = w >> 2, wn = w & 3;

  const int swz = (blockIdx.x & 7) * 64 + (blockIdx.x >> 3);
  const long m0 = (long)(swz >> 2) * 256;
  const int  n0 = (swz & 3) * 256;

  // A staging: issue q in 0..3 covers rows q*64+(tid>>3), chunk slot tid&7;
  // fetch global chunk (tid&7)^((tid>>3)&7)  [row&7 = (tid>>3)&7, carry-free]
  const float* a_sr = A + (m0 + (tid >> 3)) * 1024 + (((tid & 7) ^ ((tid >> 3) & 7)) << 2);
  // B staging: issue q in 0..1 covers rows q*128+(tid>>2), chunk slot tid&3;
  // fetch global chunk (tid&3)^((tid>>3)&3)  [(row>>1)&3 = (tid>>3)&3]
  const unsigned short* b_sr = W + (long)(n0 + (tid >> 2)) * 1024 + (((tid & 3) ^ ((tid >> 3) & 3)) << 3);

  f32x4 acc[8][4] = {};
  short8 af[8], bf[2];

  auto SA = [&](int d, int tk, int q) {
    gl2lds16(a_sr + (long)q * 65536 + tk * 32,
             smem + d * 32768 + q * 8192 + tid * 16);
  };
  auto SB = [&](int d, int tk, int q) {
    gl2lds16(b_sr + (long)q * 131072 + tk * 32,
             smem + 98304 + d * 16384 + q * 8192 + tid * 16);
  };
  auto LDA = [&](int buf) {
    const char* ab = smem + buf * 32768;
    const int c0 = c15 & 7;
#pragma unroll
    for (int m = 0; m < 8; ++m) {
      const char* rb = ab + (wm * 128 + m * 16 + c15) * 128;
      f32x4 lo = *(const f32x4*)(rb + (((2 * g)     ^ c0) << 4));
      f32x4 hi = *(const f32x4*)(rb + (((2 * g + 1) ^ c0) << 4));
      union { unsigned u[4]; short8 s; } t;
      t.u[0] = cvtpk(lo[0], lo[1]); t.u[1] = cvtpk(lo[2], lo[3]);
      t.u[2] = cvtpk(hi[0], hi[1]); t.u[3] = cvtpk(hi[2], hi[3]);
      af[m] = t.s;
    }
  };
  auto LDB1 = [&](int buf, int n) {
    return *(const short8*)(smem + 98304 + buf * 16384 +
                            (wn * 64 + n * 16 + c15) * 64 +
                            ((g ^ ((c15 >> 1) & 3)) << 4));
  };
  auto MM = [&](int h) {
    __builtin_amdgcn_s_setprio(1);
#pragma unroll
    for (int n2 = 0; n2 < 2; ++n2)
#pragma unroll
      for (int m = 0; m < 8; ++m)
        acc[m][h * 2 + n2] =
            __builtin_amdgcn_mfma_f32_16x16x32_bf16(af[m], bf[n2], acc[m][h * 2 + n2], 0, 0, 0);
    __builtin_amdgcn_s_setprio(0);
  };
  auto TILE = [&](int buf, int db, int tk, bool stage, bool drain) {
    // ph1
    LDA(buf);
    bf[0] = LDB1(buf, 0); bf[1] = LDB1(buf, 1);
    if (stage) { SA(db, tk + 2, 0); SA(db, tk + 2, 1); SA(db, tk + 2, 2); }
    bar(); MM(0); bar();
    // ph2
    bf[0] = LDB1(buf, 2); bf[1] = LDB1(buf, 3);
    if (stage) {
      SA(db, tk + 2, 3); SB(db, tk + 2, 0); SB(db, tk + 2, 1);
      vm6();
    } else if (drain) {
      vm0();
    }
    bar(); MM(1); bar();
  };

  // prologue: T0 -> buf0 (6 loads), T1 -> buf1 (6 loads); retire T0.
#pragma unroll
  for (int q = 0; q < 4; ++q) SA(0, 0, q);
  SB(0, 0, 0); SB(0, 0, 1);
#pragma unroll
  for (int q = 0; q < 4; ++q) SA(1, 1, q);
  SB(1, 1, 0); SB(1, 1, 1);
  vm6();
  bar();

#pragma unroll 1
  for (int t = 0; t < 30; t += 3) {
    TILE(0, 2, t,     true, false);
    TILE(1, 0, t + 1, true, false);
    TILE(2, 1, t + 2, true, false);
  }
  TILE(0, 2, 30, false, true);    // drain T31's loads
  TILE(1, 0, 31, false, false);

  // epilogue: acc -> cl [256][256] u16 -> rotated conflict-free copy-out
  unsigned short* cl = (unsigned short*)smem;
#pragma unroll
  for (int m = 0; m < 8; ++m)
#pragma unroll
    for (int n = 0; n < 4; ++n)
#pragma unroll
      for (int r = 0; r < 4; ++r)
        cl[(wm * 128 + m * 16 + g * 4 + r) * 256 + wn * 64 + n * 16 + c15] =
            f2b(acc[m][n][r]);
  __syncthreads();
  const int row = tid >> 1, half = tid & 1;
  unsigned short*       dst = C + (m0 + row) * 1024 + n0 + half * 128;
  const unsigned short* sl  = cl + row * 256 + half * 128;
#pragma unroll
  for (int i = 0; i < 16; ++i) {
    int c = (i + tid) & 15;     // rotation: pass lanes span all 8 bank-quads
    *(ushort8*)(dst + c * 8) = *(const ushort8*)(sl + c * 8);
  }
}

// ---------------------------------------------------------------------------
// 256x256 8-phase GEMM, bf16 A (round-11 proven + rotated epilogue)
// ---------------------------------------------------------------------------
__global__ __launch_bounds__(512, 2) void gemm256(const unsigned short* __restrict__ A,
                                                  const unsigned short* __restrict__ W,
                                                  unsigned short* __restrict__ C) {
  __shared__ __align__(16) char smem[131072];
  const int tid = threadIdx.x, lane = tid & 63, w = tid >> 6;
  const int g = lane >> 4, c15 = lane & 15;
  const int wm = w >> 2, wn = w & 3;

  const int swz = (blockIdx.x & 7) * 64 + (blockIdx.x >> 3);
  const long m0 = (long)(swz >> 2) * 256;
  const int  n0 = (swz & 3) * 256;

  const int srow = w * 16 + (lane >> 2);
  const int cswz = (lane & 3) ^ ((lane >> 3) & 3);
  const unsigned short* a_sr = A + (m0 + srow) * 1024 + cswz * 8;
  const unsigned short* b_sr = W + (long)(n0 + srow) * 1024 + cswz * 8;
  const int rswz = (g ^ ((c15 >> 1) & 3)) << 4;
  const int aoff = (wm * 128 + c15) * 64 + rswz;
  const int boff = 65536 + (wn * 64 + c15) * 64 + rswz;

  f32x4 acc[8][4] = {};
  short8 af[8], bf[2];

  auto STAGE_A = [&](int d, int kh, int tk) {
    char* dst = smem + d * 32768 + kh * 16384 + w * 1024;
    const unsigned short* src = a_sr + tk * 64 + kh * 32;
    gl2lds16(src,          dst);
    gl2lds16(src + 131072, dst + 8192);
  };
  auto STAGE_B = [&](int d, int kh, int tk) {
    char* dst = smem + 65536 + d * 32768 + kh * 16384 + w * 1024;
    const unsigned short* src = b_sr + tk * 64 + kh * 32;
    gl2lds16(src,          dst);
    gl2lds16(src + 131072, dst + 8192);
  };
  auto LDA = [&](int d, int ks) {
    const char* base = smem + d * 32768 + ks * 16384 + aoff;
#pragma unroll
    for (int m = 0; m < 8; ++m) af[m] = *(const short8*)(base + m * 1024);
  };
  auto LDB = [&](int d, int ks, int nh) {
    const char* base = smem + d * 32768 + ks * 16384 + boff + nh * 2048;
    bf[0] = *(const short8*)(base);
    bf[1] = *(const short8*)(base + 1024);
  };
  auto MM = [&](int nh) {
    __builtin_amdgcn_s_setprio(1);
#pragma unroll
    for (int n2 = 0; n2 < 2; ++n2)
#pragma unroll
      for (int m = 0; m < 8; ++m)
        acc[m][nh * 2 + n2] =
            __builtin_amdgcn_mfma_f32_16x16x32_bf16(af[m], bf[n2], acc[m][nh * 2 + n2], 0, 0, 0);
    __builtin_amdgcn_s_setprio(0);
  };

  STAGE_A(0, 0, 0); STAGE_B(0, 0, 0); STAGE_A(0, 1, 0); STAGE_B(0, 1, 0);
  vm4();
  bar();

#pragma unroll 1
  for (int tk = 0; tk < 16; tk += 2) {
    const bool more = (tk + 2 < 16);
    LDA(0, 0); LDB(0, 0, 0); STAGE_A(1, 0, tk + 1);          bar(); MM(0); bar();
    LDB(0, 0, 1);            STAGE_B(1, 0, tk + 1);  vm4();  bar(); MM(1); bar();
    LDA(0, 1); LDB(0, 1, 0); STAGE_A(1, 1, tk + 1);          bar(); MM(0); bar();
    LDB(0, 1, 1);            STAGE_B(1, 1, tk + 1);  vm4();  bar(); MM(1); bar();
    LDA(1, 0); LDB(1, 0, 0); if (more) STAGE_A(0, 0, tk + 2);        bar(); MM(0); bar();
    LDB(1, 0, 1);            if (more) STAGE_B(0, 0, tk + 2); vm4(); bar(); MM(1); bar();
    LDA(1, 1); LDB(1, 1, 0); if (more) STAGE_A(0, 1, tk + 2);        bar(); MM(0); bar();
    LDB(1, 1, 1);            if (more) STAGE_B(0, 1, tk + 2); vm4(); bar(); MM(1); bar();
  }

  unsigned short* cl = (unsigned short*)smem;
#pragma unroll
  for (int m = 0; m < 8; ++m)
#pragma unroll
    for (int n = 0; n < 4; ++n)
#pragma unroll
      for (int r = 0; r < 4; ++r)
        cl[(wm * 128 + m * 16 + g * 4 + r) * 256 + wn * 64 + n * 16 + c15] =
            f2b(acc[m][n][r]);
  __syncthreads();
  const int row = tid >> 1, half = tid & 1;
  unsigned short*       dst = C + (m0 + row) * 1024 + n0 + half * 128;
  const unsigned short* sl  = cl + row * 256 + half * 128;
#pragma unroll
  for (int i = 0; i < 16; ++i) {
    int c = (i + tid) & 15;     // rotated: conflict-free copy-out
    *(ushort8*)(dst + c * 8) = *(const ushort8*)(sl + c * 8);
  }
}

// ---------------------------------------------------------------------------
// 128x128 2-phase GEMM (proven) for the small projections (M=512)
// ---------------------------------------------------------------------------
template <bool OUT_F32B>
__global__ __launch_bounds__(256) void gemm_bf16(const unsigned short* __restrict__ A,
                                                 const unsigned short* __restrict__ W,
                                                 void* __restrict__ Cp,
                                                 const float* __restrict__ bias) {
  __shared__ __align__(16) char smem[34816];
  const int tid = threadIdx.x, lane = tid & 63, wv = tid >> 6;
  const int g = lane >> 4, c15 = lane & 15;
  const int wm = wv >> 1, wn = wv & 1;

  const int nwg = gridDim.x;
  const int swz = (blockIdx.x & 7) * (nwg >> 3) + (blockIdx.x >> 3);
  const long m0 = (long)(swz >> 3) * 128;
  const int  n0 = (swz & 7) * 128;

  const int srow = lane >> 2, scol = (lane & 3) * 8;
  const unsigned short* a_src = A + (m0 + srow) * 1024 + scol;
  const unsigned short* b_src = W + (long)(n0 + srow) * 1024 + scol;

  f32x4 acc[4][4] = {};

  auto stage = [&](int buf, int kt) {
    unsigned short* al = (unsigned short*)(smem + buf * 8192);
    unsigned short* bl = (unsigned short*)(smem + 16384 + buf * 8192);
#pragma unroll
    for (int q = 0; q < 2; ++q) {
      const int rbase = q * 64 + wv * 16;
      gl2lds16(a_src + (long)rbase * 1024 + kt * 32, al + rbase * 32);
      gl2lds16(b_src + (long)rbase * 1024 + kt * 32, bl + rbase * 32);
    }
  };

  stage(0, 0);
  __syncthreads();

  int cur = 0;
  for (int kt = 0; kt < 32; ++kt) {
    if (kt + 1 < 32) stage(cur ^ 1, kt + 1);
    const unsigned short* al = (const unsigned short*)(smem + cur * 8192);
    const unsigned short* bl = (const unsigned short*)(smem + 16384 + cur * 8192);
    short8 af[4];
#pragma unroll
    for (int m = 0; m < 4; ++m)
      af[m] = *(const short8*)&al[(wm * 64 + m * 16 + c15) * 32 + g * 8];
#pragma unroll
    for (int n = 0; n < 4; ++n) {
      short8 b8 = *(const short8*)&bl[(wn * 64 + n * 16 + c15) * 32 + g * 8];
#pragma unroll
      for (int m = 0; m < 4; ++m)
        acc[m][n] = __builtin_amdgcn_mfma_f32_16x16x32_bf16(af[m], b8, acc[m][n], 0, 0, 0);
    }
    __syncthreads();
    cur ^= 1;
  }

  if constexpr (OUT_F32B) {
    float* Cf = (float*)Cp;
#pragma unroll
    for (int m = 0; m < 4; ++m)
#pragma unroll
      for (int n = 0; n < 4; ++n)
#pragma unroll
        for (int r = 0; r < 4; ++r) {
          long row = m0 + wm * 64 + m * 16 + g * 4 + r;
          int  col = n0 + wn * 64 + n * 16 + c15;
          Cf[row * 1024 + col] = acc[m][n][r] + bias[col];
        }
  } else {
    unsigned short* c_lds = (unsigned short*)smem;
#pragma unroll
    for (int m = 0; m < 4; ++m)
#pragma unroll
      for (int n = 0; n < 4; ++n)
#pragma unroll
        for (int r = 0; r < 4; ++r)
          c_lds[(wm * 64 + m * 16 + g * 4 + r) * 132 + wn * 64 + n * 16 + c15] =
              f2b(acc[m][n][r]);
    __syncthreads();
    unsigned short* Cb = (unsigned short*)Cp;
    const int row = tid >> 1, half = tid & 1;
    unsigned short*       dst = Cb + (m0 + row) * 1024 + n0 + half * 64;
    const unsigned short* sl  = &c_lds[row * 132 + half * 64];
#pragma unroll
    for (int i = 0; i < 8; ++i)
      *(ushort8*)(dst + i * 8) = *(const ushort8*)(sl + i * 8);
  }
}

// ---------------------------------------------------------------------------
// Attention pass 1 (L-split x4): partial rowsums over 1024 keys per block.
// ---------------------------------------------------------------------------
__global__ __launch_bounds__(512) void attn_pass1(const unsigned short* __restrict__ q_b,
                                                  const unsigned short* __restrict__ k_b,
                                                  float* __restrict__ rs_part) {
  __shared__ unsigned short q_lds[64][72];
  __shared__ unsigned short k_lds[128][72];
  __shared__ float rs_lds[8][64];
  const int bh = blockIdx.x >> 2, ch = blockIdx.x & 3;
  const int b = bh >> 4, h = bh & 15;
  const int tid = threadIdx.x;
  const int w = tid >> 6, lane = tid & 63;
  const int g = lane >> 4, c15 = lane & 15;

  {
    int slot = tid >> 3, cc = (tid & 7) * 8;
    *(ushort8*)&q_lds[slot][cc] =
        *(const ushort8*)(q_b + (long)(b * 64 + slot) * 1024 + h * 64 + cc);
  }

  float rs[4][4] = {};
  const long kbase = (long)b * L_ * D_ + h * 64;
  const int  sl = tid >> 2, sc = (tid & 3) * 16;

  for (int it = ch * 8; it < ch * 8 + 8; ++it) {
    const int l0 = it * 128;
    ushort8 k0 = *(const ushort8*)(k_b + kbase + (long)(l0 + sl) * 1024 + sc);
    ushort8 k1 = *(const ushort8*)(k_b + kbase + (long)(l0 + sl) * 1024 + sc + 8);
    __syncthreads();
    *(ushort8*)&k_lds[sl][sc]     = k0;
    *(ushort8*)&k_lds[sl][sc + 8] = k1;
    __syncthreads();

    f32x4 s[4] = {};
#pragma unroll
    for (int ks = 0; ks < 2; ++ks) {
      short8 bf = *(const short8*)&k_lds[w * 16 + c15][ks * 32 + g * 8];
#pragma unroll
      for (int m = 0; m < 4; ++m) {
        short8 af = *(const short8*)&q_lds[m * 16 + c15][ks * 32 + g * 8];
        s[m] = __builtin_amdgcn_mfma_f32_16x16x32_bf16(af, bf, s[m], 0, 0, 0);
      }
    }
    float mx = -1e30f;
#pragma unroll
    for (int m = 0; m < 4; ++m)
#pragma unroll
      for (int r = 0; r < 4; ++r) mx = fmaxf(mx, s[m][r]);
    mx = fmaxf(mx, __shfl_xor(mx, 16));
    mx = fmaxf(mx, __shfl_xor(mx, 32));
    float sum = 0.f, p[4][4];
#pragma unroll
    for (int m = 0; m < 4; ++m)
#pragma unroll
      for (int r = 0; r < 4; ++r) { p[m][r] = __expf((s[m][r] - mx) * SCALE_); sum += p[m][r]; }
    sum += __shfl_xor(sum, 16);
    sum += __shfl_xor(sum, 32);
    float rinv = 1.0f / sum;
#pragma unroll
    for (int m = 0; m < 4; ++m)
#pragma unroll
      for (int r = 0; r < 4; ++r) rs[m][r] += p[m][r] * rinv;
  }
#pragma unroll
  for (int m = 0; m < 4; ++m)
#pragma unroll
    for (int r = 0; r < 4; ++r) {
      float v = rs[m][r];
      v += __shfl_xor(v, 1); v += __shfl_xor(v, 2);
      v += __shfl_xor(v, 4); v += __shfl_xor(v, 8);
      if (c15 == 0) rs_lds[w][m * 16 + g * 4 + r] = v;
    }
  __syncthreads();
  if (tid < 64) {
    float t = 0.f;
#pragma unroll
    for (int w2 = 0; w2 < 8; ++w2) t += rs_lds[w2][tid];
    rs_part[(bh * 4 + ch) * 64 + tid] = t;
  }
}

// ---------------------------------------------------------------------------
// Attention pass 2 (L-split x4): recompute softmax, scale, write attn fp32
// (nontemporal), PV partial -> op_part fp32.
// ---------------------------------------------------------------------------
__global__ __launch_bounds__(512) void attn_pass2(const unsigned short* __restrict__ q_b,
                                                  const unsigned short* __restrict__ k_b,
                                                  const unsigned short* __restrict__ v_b,
                                                  const float* __restrict__ rs_part,
                                                  float* __restrict__ attn,
                                                  float* __restrict__ op_part) {
  __shared__ unsigned short q_lds[64][72];
  __shared__ unsigned short k_lds[128][72];
  __shared__ unsigned short vt_lds[64][136];
  __shared__ unsigned short pt_lds[64][136];
  const int bh = blockIdx.x >> 2, ch = blockIdx.x & 3;
  const int b = bh >> 4, h = bh & 15;
  const int tid = threadIdx.x;
  const int w = tid >> 6, lane = tid & 63;
  const int g = lane >> 4, c15 = lane & 15;

  {
    int slot = tid >> 3, cc = (tid & 7) * 8;
    *(ushort8*)&q_lds[slot][cc] =
        *(const ushort8*)(q_b + (long)(b * 64 + slot) * 1024 + h * 64 + cc);
  }

  float inv_r[4][4];
#pragma unroll
  for (int m = 0; m < 4; ++m)
#pragma unroll
    for (int r = 0; r < 4; ++r) {
      int slot = m * 16 + g * 4 + r;
      float s = 0.f;
#pragma unroll
      for (int c = 0; c < 4; ++c) s += rs_part[(bh * 4 + c) * 64 + slot];
      inv_r[m][r] = 1.0f / (s + 1e-8f);
    }

  f32x4 oacc[2] = {};
  const int m_pv = w >> 1, n_pv0 = (w & 1) * 2;
  float* attn_base = attn + (long)bh * KS_ * L_;
  const long base_bld = (long)b * L_ * D_ + h * 64;
  const int  sl = tid >> 2, sc = (tid & 3) * 16;

  for (int it = ch * 8; it < ch * 8 + 8; ++it) {
    const int l0 = it * 128;
    ushort8 k0 = *(const ushort8*)(k_b + base_bld + (long)(l0 + sl) * 1024 + sc);
    ushort8 k1 = *(const ushort8*)(k_b + base_bld + (long)(l0 + sl) * 1024 + sc + 8);
    ushort8 v0 = *(const ushort8*)(v_b + base_bld + (long)(l0 + sl) * 1024 + sc);
    ushort8 v1 = *(const ushort8*)(v_b + base_bld + (long)(l0 + sl) * 1024 + sc + 8);
    __syncthreads();
    *(ushort8*)&k_lds[sl][sc]     = k0;
    *(ushort8*)&k_lds[sl][sc + 8] = k1;
#pragma unroll
    for (int j = 0; j < 8; ++j) {
      vt_lds[sc + j][sl]     = v0[j];
      vt_lds[sc + 8 + j][sl] = v1[j];
    }
    __syncthreads();

    f32x4 s[4] = {};
#pragma unroll
    for (int ks = 0; ks < 2; ++ks) {
      short8 bf = *(const short8*)&k_lds[w * 16 + c15][ks * 32 + g * 8];
#pragma unroll
      for (int m = 0; m < 4; ++m) {
        short8 af = *(const short8*)&q_lds[m * 16 + c15][ks * 32 + g * 8];
        s[m] = __builtin_amdgcn_mfma_f32_16x16x32_bf16(af, bf, s[m], 0, 0, 0);
      }
    }
    float mx = -1e30f;
#pragma unroll
    for (int m = 0; m < 4; ++m)
#pragma unroll
      for (int r = 0; r < 4; ++r) mx = fmaxf(mx, s[m][r]);
    mx = fmaxf(mx, __shfl_xor(mx, 16));
    mx = fmaxf(mx, __shfl_xor(mx, 32));
    float sum = 0.f, p[4][4];
#pragma unroll
    for (int m = 0; m < 4; ++m)
#pragma unroll
      for (int r = 0; r < 4; ++r) { p[m][r] = __expf((s[m][r] - mx) * SCALE_); sum += p[m][r]; }
    sum += __shfl_xor(sum, 16);
    sum += __shfl_xor(sum, 32);
    float rinv = 1.0f / sum;

    const int lloc = w * 16 + c15;
#pragma unroll
    for (int m = 0; m < 4; ++m)
#pragma unroll
      for (int r = 0; r < 4; ++r) {
        float ps = p[m][r] * rinv * inv_r[m][r];
        __builtin_nontemporal_store(ps,
            &attn_base[(long)(m * 16 + g * 4 + r) * L_ + l0 + lloc]);
        pt_lds[m * 16 + g * 4 + r][lloc] = f2b(ps);
      }
    __syncthreads();

#pragma unroll
    for (int ks = 0; ks < 4; ++ks) {
      short8 pa = *(const short8*)&pt_lds[m_pv * 16 + c15][ks * 32 + g * 8];
#pragma unroll
      for (int n2 = 0; n2 < 2; ++n2) {
        short8 vb = *(const short8*)&vt_lds[(n_pv0 + n2) * 16 + c15][ks * 32 + g * 8];
        oacc[n2] = __builtin_amdgcn_mfma_f32_16x16x32_bf16(pa, vb, oacc[n2], 0, 0, 0);
      }
    }
  }

#pragma unroll
  for (int n2 = 0; n2 < 2; ++n2)
#pragma unroll
    for (int r = 0; r < 4; ++r) {
      int slot = m_pv * 16 + g * 4 + r;
      int c    = (n_pv0 + n2) * 16 + c15;
      op_part[((long)(bh * 4 + ch) * 64 + slot) * 64 + c] = oacc[n2][r];
    }
}

// ---------------------------------------------------------------------------
// Reduce PV chunk-partials -> oh bf16 [512][1024]
// ---------------------------------------------------------------------------
__global__ __launch_bounds__(256) void oh_red(const float* __restrict__ op_part,
                                              unsigned short* __restrict__ oh) {
  int i = blockIdx.x * 256 + threadIdx.x;
  int c = i & 63, slot = (i >> 6) & 63, bh = i >> 12;
  float s = 0.f;
#pragma unroll
  for (int ch = 0; ch < 4; ++ch)
    s += op_part[((long)(bh * 4 + ch) * 64 + slot) * 64 + c];
  int b = bh >> 4, h = bh & 15;
  oh[(long)(b * 64 + slot) * 1024 + h * 64 + c] = f2b(s);
}

// ---------------------------------------------------------------------------
extern "C" void kernel_launch(void* const* d_in, const int* in_sizes, int n_in,
                              void* d_out, int out_size, void* d_ws, size_t ws_size,
                              hipStream_t stream) {
  (void)in_sizes; (void)n_in; (void)out_size; (void)ws_size;
  const float* query = (const float*)d_in[0];
  const float* key   = (const float*)d_in[1];
  const float* value = (const float*)d_in[2];
  const float* Wq    = (const float*)d_in[3];
  const float* Wk    = (const float*)d_in[4];
  const float* Wv    = (const float*)d_in[5];
  const float* Wo    = (const float*)d_in[6];
  const float* bo    = (const float*)d_in[7];

  char* ws = (char*)d_ws;
  unsigned short* w_all   = (unsigned short*)ws;                        // 8 MB
  unsigned short* wq_b    = w_all;
  unsigned short* wk_b    = w_all + (1u << 20);
  unsigned short* wv_b    = w_all + (2u << 20);
  unsigned short* wo_b    = w_all + (3u << 20);
  unsigned short* qin_b   = (unsigned short*)(ws + ((size_t)8  << 20)); // 1 MB
  unsigned short* q_b     = (unsigned short*)(ws + ((size_t)9  << 20)); // 1 MB
  unsigned short* oh_b    = (unsigned short*)(ws + ((size_t)10 << 20)); // 1 MB
  float*          rs_part = (float*)         (ws + ((size_t)11 << 20)); // 128 KB
  float*          op_part = (float*)         (ws + ((size_t)12 << 20)); // 8 MB
  unsigned short* k_b     = (unsigned short*)(ws + ((size_t)20 << 20)); // 64 MB
  unsigned short* v_b     = (unsigned short*)(ws + ((size_t)84 << 20)); // 64 MB

  float* out  = (float*)d_out;
  float* attn = out + (size_t)B_ * KS_ * D_;

  // converted V input lives in the not-yet-written attn output region
  unsigned short* vin_b = (unsigned short*)attn;

  wcvt<<<4608, 256, 0, stream>>>(Wq, Wk, Wv, Wo, query, w_all, qin_b);
  cvt1<<<4096, 256, 0, stream>>>(value, vin_b, 4194304);

  gemm_bf16<false><<<32, 256, 0, stream>>>(qin_b, wq_b, q_b, nullptr);
  gemm256f32<<<512, 512, 0, stream>>>(key,   wk_b, k_b);   // fused-cvt A/B test
  gemm256   <<<512, 512, 0, stream>>>(vin_b, wv_b, v_b);   // proven path

  attn_pass1<<<512, 512, 0, stream>>>(q_b, k_b, rs_part);
  attn_pass2<<<512, 512, 0, stream>>>(q_b, k_b, v_b, rs_part, attn, op_part);
  oh_red<<<2048, 256, 0, stream>>>(op_part, oh_b);

  gemm_bf16<true><<<32, 256, 0, stream>>>(oh_b, wo_b, out, bo);
}